// Round 7
// baseline (535.524 us; speedup 1.0000x reference)
//
#include <hip/hip_runtime.h>
#include <cstdint>
#include <cstddef>

constexpr int DIMS = 128;
constexpr int NB = 64;  // degree bins for counting sort (clamped)

typedef __attribute__((ext_vector_type(8))) short bf16x8;
typedef __attribute__((ext_vector_type(8))) unsigned short ushort8v;
typedef __attribute__((ext_vector_type(4))) float f32x4;

__device__ __forceinline__ unsigned short f2b(float f) {
    uint32_t u = __builtin_bit_cast(uint32_t, f);
    uint32_t r = (u + 0x7FFFu + ((u >> 16) & 1u)) >> 16;
    return (unsigned short)r;
}
__device__ __forceinline__ float b2f(unsigned short h) {
    uint32_t u = ((uint32_t)h) << 16;
    return __builtin_bit_cast(float, u);
}

// ---------------- degree + per-edge slot ----------------
__global__ void k_count_slot(const int* __restrict__ dst, int* __restrict__ cnt,
                             int* __restrict__ slot, int E) {
    int e = blockIdx.x * blockDim.x + threadIdx.x;
    if (e < E) slot[e] = atomicAdd(&cnt[dst[e]], 1);
}

__global__ void k_dinv2(const int* __restrict__ cnt, float* __restrict__ dinv, int N) {
    int i = blockIdx.x * blockDim.x + threadIdx.x;
    if (i < N) dinv[i] = rsqrtf((float)(cnt[i] + 1));
}

// bump-allocated CSR row offsets
__global__ void k_alloc(const int* __restrict__ cnt, int* __restrict__ row_ptr,
                        int* __restrict__ bump, int N) {
    int i = blockIdx.x * blockDim.x + threadIdx.x;
    int lane = threadIdx.x & 63;
    int v = (i < N) ? cnt[i] : 0;
    int x = v;
#pragma unroll
    for (int d = 1; d < 64; d <<= 1) {
        int y = __shfl_up(x, d);
        if (lane >= d) x += y;
    }
    int total = __shfl(x, 63);
    int base = 0;
    if (lane == 0) base = atomicAdd(bump, total);
    base = __shfl(base, 0);
    if (i < N) row_ptr[i] = base + x - v;
}

// atomic-free bucket fill
__global__ void k_fill3(const int* __restrict__ src, const int* __restrict__ dst,
                        const int* __restrict__ row_ptr, const int* __restrict__ slot,
                        int* __restrict__ col, int E) {
    int e = blockIdx.x * blockDim.x + threadIdx.x;
    if (e >= E) return;
    col[row_ptr[dst[e]] + slot[e]] = src[e];
}

// ---------------- counting sort of nodes by degree ----------------
__global__ void k_hist(const int* __restrict__ cnt, int* __restrict__ hist, int N) {
    __shared__ int h[NB];
    if (threadIdx.x < NB) h[threadIdx.x] = 0;
    __syncthreads();
    int i = blockIdx.x * blockDim.x + threadIdx.x;
    if (i < N) {
        int d = cnt[i]; if (d > NB - 1) d = NB - 1;
        atomicAdd(&h[d], 1);
    }
    __syncthreads();
    if (threadIdx.x < NB) {
        int v = h[threadIdx.x];
        if (v) atomicAdd(&hist[threadIdx.x], v);
    }
}

__global__ void k_scan(const int* __restrict__ hist, int* __restrict__ binBase) {
    int lane = threadIdx.x;  // blockDim.x == 64
    int v = hist[lane];
    int x = v;
#pragma unroll
    for (int d = 1; d < 64; d <<= 1) {
        int y = __shfl_up(x, d);
        if (lane >= d) x += y;
    }
    binBase[lane] = x - v;
}

__global__ void k_sortscatter(const int* __restrict__ cnt, const int* __restrict__ binBase,
                              int* __restrict__ binCursor, int* __restrict__ perm, int N) {
    __shared__ int lh[NB];
    __shared__ int lbase[NB];
    if (threadIdx.x < NB) lh[threadIdx.x] = 0;
    __syncthreads();
    int i = blockIdx.x * blockDim.x + threadIdx.x;
    int d = 0, lr = 0;
    bool valid = (i < N);
    if (valid) {
        d = cnt[i]; if (d > NB - 1) d = NB - 1;
        lr = atomicAdd(&lh[d], 1);
    }
    __syncthreads();
    if (threadIdx.x < NB) {
        int c = lh[threadIdx.x];
        lbase[threadIdx.x] = c ? atomicAdd(&binCursor[threadIdx.x], c) : 0;
    }
    __syncthreads();
    if (valid) perm[binBase[d] + lbase[d] + lr] = i;
}

// ---------------- f32 -> bf16 row cast ----------------
__global__ void k_cast(const float* __restrict__ X, unsigned short* __restrict__ Y, int n8) {
    int i = blockIdx.x * blockDim.x + threadIdx.x;
    if (i >= n8) return;
    const float4* p = (const float4*)X + (size_t)i * 2;
    float4 a = p[0], b = p[1];
    ushort8v o;
    o[0] = f2b(a.x); o[1] = f2b(a.y); o[2] = f2b(a.z); o[3] = f2b(a.w);
    o[4] = f2b(b.x); o[5] = f2b(b.y); o[6] = f2b(b.z); o[7] = f2b(b.w);
    *(ushort8v*)&Y[(size_t)i * 8] = o;
}

// ---------------- W pack (all 4 weights, one launch) ----------------
__global__ void k_wpack4(const float* __restrict__ W0, const float* __restrict__ W1,
                         const float* __restrict__ W2, const float* __restrict__ W3,
                         unsigned short* __restrict__ out) {
    int t = blockIdx.x * blockDim.x + threadIdx.x;  // 0..2047
    if (t >= 2048) return;
    const float* W = (blockIdx.y == 0) ? W0 : (blockIdx.y == 1) ? W1
                   : (blockIdx.y == 2) ? W2 : W3;
    unsigned short* o = out + (size_t)blockIdx.y * 16384;
    int lane = t & 63;
    int nt = (t >> 6) & 7;
    int kk = t >> 9;
    int n = nt * 16 + (lane & 15);
    int k0 = kk * 32 + (lane >> 4) * 8;
    ushort8v h8;
#pragma unroll
    for (int j = 0; j < 8; ++j) h8[j] = f2b(W[(size_t)(k0 + j) * DIMS + n]);
    *(ushort8v*)&o[(size_t)t * 8] = h8;
}

// ---------------- gather (bf16 in/out), degree-sorted, 16 lanes/node ----------------
__global__ __launch_bounds__(256) void k_gather_b4(
    const unsigned short* __restrict__ Xb, const float* __restrict__ dinv,
    const int* __restrict__ row_ptr, const int* __restrict__ cnt,
    const int* __restrict__ col, const int* __restrict__ perm,
    unsigned short* __restrict__ aggb, int N)
{
    int t = blockIdx.x * blockDim.x + threadIdx.x;
    int g = t >> 4;
    if (g >= N) return;
    const int node = perm[g];
    const size_t base = (size_t)(t & 15) * 8;

    float ds = dinv[node];
    float w0 = ds * ds;
    ushort8v sv = *(const ushort8v*)&Xb[(size_t)node * DIMS + base];
    float acc[8];
#pragma unroll
    for (int q = 0; q < 8; ++q) acc[q] = b2f(sv[q]) * w0;

    int beg = row_ptr[node];
    int m = cnt[node];
    int j = 0;
    for (; j + 1 < m; j += 2) {
        int s0 = col[beg + j], s1 = col[beg + j + 1];
        float wa = ds * dinv[s0], wb = ds * dinv[s1];
        ushort8v v0 = *(const ushort8v*)&Xb[(size_t)s0 * DIMS + base];
        ushort8v v1 = *(const ushort8v*)&Xb[(size_t)s1 * DIMS + base];
#pragma unroll
        for (int q = 0; q < 8; ++q) acc[q] = fmaf(wa, b2f(v0[q]), acc[q]);
#pragma unroll
        for (int q = 0; q < 8; ++q) acc[q] = fmaf(wb, b2f(v1[q]), acc[q]);
    }
    if (j < m) {
        int s0 = col[beg + j];
        float wa = ds * dinv[s0];
        ushort8v v0 = *(const ushort8v*)&Xb[(size_t)s0 * DIMS + base];
#pragma unroll
        for (int q = 0; q < 8; ++q) acc[q] = fmaf(wa, b2f(v0[q]), acc[q]);
    }
    ushort8v o;
#pragma unroll
    for (int q = 0; q < 8; ++q) o[q] = f2b(acc[q]);
    *(ushort8v*)&aggb[(size_t)node * DIMS + base] = o;
}

// ---------------- MFMA dual-GEMM + coupling, v4: 512 thr, 128-row tile ----------------
__global__ __launch_bounds__(512) void k_mfma_couple4(
    const unsigned short* __restrict__ Ab, const unsigned short* __restrict__ Wpk,
    const float* __restrict__ bs, const float* __restrict__ bt,
    const float* __restrict__ Xo, float* __restrict__ Out,
    unsigned short* OutB, int N, int ntiles)
{
    __shared__ unsigned short lds[32768];  // 64 KB: Ws frags | Wt frags
    for (int i = threadIdx.x; i < 4096; i += 512)
        *(ushort8v*)&lds[(size_t)i * 8] = *(const ushort8v*)&Wpk[(size_t)i * 8];
    __syncthreads();
    const unsigned short* wsf = lds;
    const unsigned short* wtf = lds + 16384;

    const int wave = threadIdx.x >> 6, lane = threadIdx.x & 63;
    const int rsub = lane & 15;
    const int ksub = (lane >> 4) * 8;
    const int csub = (lane >> 4) * 4;

    for (int tile = blockIdx.x; tile < ntiles; tile += gridDim.x) {
        const int m = tile * 128 + wave * 16 + rsub;
        const int mld = (m < N) ? m : (N - 1);
        const bool valid = (m < N);

        bf16x8 af[4];
#pragma unroll
        for (int kk = 0; kk < 4; ++kk)
            af[kk] = *(const bf16x8*)&Ab[(size_t)mld * DIMS + kk * 32 + ksub];

        f32x4 acc_s[8], acc_t[8];
#pragma unroll
        for (int nt = 0; nt < 8; ++nt) {
            acc_s[nt] = (f32x4){0.f, 0.f, 0.f, 0.f};
            acc_t[nt] = (f32x4){0.f, 0.f, 0.f, 0.f};
        }

#pragma unroll
        for (int kk = 0; kk < 4; ++kk) {
#pragma unroll
            for (int nt = 0; nt < 8; ++nt) {
                const int fi = ((kk * 8 + nt) * 64 + lane) * 8;
                bf16x8 ws = *(const bf16x8*)&wsf[fi];
                bf16x8 wt = *(const bf16x8*)&wtf[fi];
                acc_s[nt] = __builtin_amdgcn_mfma_f32_16x16x32_bf16(ws, af[kk], acc_s[nt], 0, 0, 0);
                acc_t[nt] = __builtin_amdgcn_mfma_f32_16x16x32_bf16(wt, af[kk], acc_t[nt], 0, 0, 0);
            }
        }

        if (valid) {
#pragma unroll
            for (int nt = 0; nt < 8; ++nt) {
                const int c4 = nt * 16 + csub;
                float4 bsv = *(const float4*)&bs[c4];
                float4 btv = *(const float4*)&bt[c4];
                float4 xo  = *(const float4*)&Xo[(size_t)m * DIMS + c4];
                float4 o;
                o.x = xo.x * expf(tanhf(acc_s[nt][0] + bsv.x)) + (acc_t[nt][0] + btv.x);
                o.y = xo.y * expf(tanhf(acc_s[nt][1] + bsv.y)) + (acc_t[nt][1] + btv.y);
                o.z = xo.z * expf(tanhf(acc_s[nt][2] + bsv.z)) + (acc_t[nt][2] + btv.z);
                o.w = xo.w * expf(tanhf(acc_s[nt][3] + bsv.w)) + (acc_t[nt][3] + btv.w);
                *(float4*)&Out[(size_t)m * DIMS + c4] = o;
                if (OutB) {
                    ushort4 ob;
                    ob.x = f2b(o.x); ob.y = f2b(o.y); ob.z = f2b(o.z); ob.w = f2b(o.w);
                    *(ushort4*)&OutB[(size_t)m * DIMS + c4] = ob;
                }
            }
        }
    }
}

// ---------------- f32 fallback kernels ----------------
__global__ void k_fill(const int* __restrict__ src, const int* __restrict__ dst,
                       const int* __restrict__ row_ptr, int* __restrict__ cursor,
                       const float* __restrict__ dinv,
                       int* __restrict__ col, float* __restrict__ wgt, int E) {
    int e = blockIdx.x * blockDim.x + threadIdx.x;
    if (e >= E) return;
    int s = src[e], d = dst[e];
    int pos = row_ptr[d] + atomicAdd(&cursor[d], 1);
    col[pos] = s;
    wgt[pos] = dinv[s] * dinv[d];
}

__global__ __launch_bounds__(256) void k_gather(
    const float4* __restrict__ X4, const float* __restrict__ dinv,
    const int* __restrict__ row_ptr, const int* __restrict__ cnt,
    const int* __restrict__ col, const float* __restrict__ wgt,
    float4* __restrict__ agg4, int N)
{
    int t = blockIdx.x * blockDim.x + threadIdx.x;
    int node = t >> 5;
    if (node >= N) return;
    int lane = t & 31;
    float ds = dinv[node];
    float w0 = ds * ds;
    float4 acc = X4[(size_t)node * 32 + lane];
    acc.x *= w0; acc.y *= w0; acc.z *= w0; acc.w *= w0;
    int beg = row_ptr[node];
    int m = cnt[node];
    for (int j = 0; j < m; ++j) {
        int s0 = col[beg + j];
        float wa = wgt[beg + j];
        float4 v0 = X4[(size_t)s0 * 32 + lane];
        acc.x = fmaf(wa, v0.x, acc.x); acc.y = fmaf(wa, v0.y, acc.y);
        acc.z = fmaf(wa, v0.z, acc.z); acc.w = fmaf(wa, v0.w, acc.w);
    }
    agg4[(size_t)node * 32 + lane] = acc;
}

__global__ __launch_bounds__(256) void k_gemm_couple(
    const float* A, const float* __restrict__ Ws, const float* __restrict__ bs,
    const float* __restrict__ Wt, const float* __restrict__ bt,
    const float* __restrict__ Xo, float* Out, int N)
{
    constexpr int TM = 64, TK = 16;
    __shared__ float As[TK][TM + 4];
    __shared__ float Ss[TK][DIMS];
    __shared__ float St[TK][DIMS];
    const int tid = threadIdx.x;
    const int ty = tid >> 4, tx = tid & 15;
    const int r0 = ty * 4, c0 = tx * 8;
    const int block_row = blockIdx.x * TM;

    float acc_s[4][8], acc_t[4][8];
#pragma unroll
    for (int r = 0; r < 4; ++r)
#pragma unroll
        for (int c = 0; c < 8; ++c) { acc_s[r][c] = 0.f; acc_t[r][c] = 0.f; }

    const int ar = tid >> 2;
    const int aq = tid & 3;
    int arow = block_row + ar;
    if (arow >= N) arow = N - 1;

    for (int k0 = 0; k0 < DIMS; k0 += TK) {
        __syncthreads();
        {
            float4 v = *(const float4*)&A[(size_t)arow * DIMS + k0 + aq * 4];
            As[aq * 4 + 0][ar] = v.x;
            As[aq * 4 + 1][ar] = v.y;
            As[aq * 4 + 2][ar] = v.z;
            As[aq * 4 + 3][ar] = v.w;
        }
#pragma unroll
        for (int i = 0; i < 2; ++i) {
            int idx = tid + i * 256;
            int kk = idx >> 5;
            int j4 = idx & 31;
            *(float4*)&Ss[kk][j4 * 4] = *(const float4*)&Ws[(size_t)(k0 + kk) * DIMS + j4 * 4];
            *(float4*)&St[kk][j4 * 4] = *(const float4*)&Wt[(size_t)(k0 + kk) * DIMS + j4 * 4];
        }
        __syncthreads();
#pragma unroll
        for (int k = 0; k < TK; ++k) {
            float4 av = *(const float4*)&As[k][r0];
            float a[4] = {av.x, av.y, av.z, av.w};
            float ws8[8], wt8[8];
            *(float4*)&ws8[0] = *(const float4*)&Ss[k][c0];
            *(float4*)&ws8[4] = *(const float4*)&Ss[k][c0 + 4];
            *(float4*)&wt8[0] = *(const float4*)&St[k][c0];
            *(float4*)&wt8[4] = *(const float4*)&St[k][c0 + 4];
#pragma unroll
            for (int r = 0; r < 4; ++r)
#pragma unroll
                for (int c = 0; c < 8; ++c) {
                    acc_s[r][c] = fmaf(a[r], ws8[c], acc_s[r][c]);
                    acc_t[r][c] = fmaf(a[r], wt8[c], acc_t[r][c]);
                }
        }
    }

    float bsv[8], btv[8];
    *(float4*)&bsv[0] = *(const float4*)&bs[c0];
    *(float4*)&bsv[4] = *(const float4*)&bs[c0 + 4];
    *(float4*)&btv[0] = *(const float4*)&bt[c0];
    *(float4*)&btv[4] = *(const float4*)&bt[c0 + 4];
#pragma unroll
    for (int r = 0; r < 4; ++r) {
        int row = block_row + r0 + r;
        if (row < N) {
            float xo[8];
            *(float4*)&xo[0] = *(const float4*)&Xo[(size_t)row * DIMS + c0];
            *(float4*)&xo[4] = *(const float4*)&Xo[(size_t)row * DIMS + c0 + 4];
            float o[8];
#pragma unroll
            for (int c = 0; c < 8; ++c) {
                float s = tanhf(acc_s[r][c] + bsv[c]);
                float t = acc_t[r][c] + btv[c];
                o[c] = xo[c] * expf(s) + t;
            }
            *(float4*)&Out[(size_t)row * DIMS + c0] = *(const float4*)&o[0];
            *(float4*)&Out[(size_t)row * DIMS + c0 + 4] = *(const float4*)&o[4];
        }
    }
}

extern "C" void kernel_launch(void* const* d_in, const int* in_sizes, int n_in,
                              void* d_out, int out_size, void* d_ws, size_t ws_size,
                              hipStream_t stream) {
    const float* x_main  = (const float*)d_in[0];
    const float* x_guide = (const float*)d_in[1];
    const int*   ei      = (const int*)d_in[2];
    const float* Ws1 = (const float*)d_in[3];
    const float* bs1 = (const float*)d_in[4];
    const float* Wt1 = (const float*)d_in[5];
    const float* bt1 = (const float*)d_in[6];
    const float* Ws2 = (const float*)d_in[7];
    const float* bs2 = (const float*)d_in[8];
    const float* Wt2 = (const float*)d_in[9];
    const float* bt2 = (const float*)d_in[10];

    const int N = in_sizes[0] / DIMS;
    const int E = in_sizes[2] / 2;
    const int* src = ei;
    const int* dst = ei + E;

    float* out_main  = (float*)d_out;
    float* out_guide = out_main + (size_t)N * DIMS;

    // ---- ws layout ----
    char* w = (char*)d_ws;
    size_t off = 0;
    auto alloc = [&](size_t bytes) { size_t o = off; off = (off + bytes + 15) & ~(size_t)15; return o; };
    int*   cnt      = (int*)(w + alloc((size_t)N * 4));
    int*   row_ptr  = (int*)(w + alloc((size_t)N * 4));
    int*   bumpBlk  = (int*)(w + alloc(1024));   // bump | hist[64] | binCursor[64]
    int*   bump      = bumpBlk;
    int*   hist      = bumpBlk + 64;
    int*   binCursor = bumpBlk + 128;
    int*   binBase  = (int*)(w + alloc(256));
    float* dinv     = (float*)(w + alloc((size_t)N * 4));
    int*   col      = (int*)(w + alloc((size_t)E * 4));
    int*   perm     = (int*)(w + alloc((size_t)N * 4));
    size_t base_end = off;
    unsigned short* xb   = (unsigned short*)(w + alloc((size_t)N * DIMS * 2));
    unsigned short* aggb = (unsigned short*)(w + alloc((size_t)N * DIMS * 2));
    unsigned short* wpk  = (unsigned short*)(w + alloc((size_t)4 * 16384 * 2));
    size_t needed_mfma = off;
    int* slot = (int*)aggb;   // aliases aggb, consumed before gather writes aggb
    int*   cursor_fb = (int*)(w + base_end);
    float* wgt_fb    = (float*)(w + base_end + (((size_t)N * 4 + 15) & ~(size_t)15));
    size_t needed_f32 = base_end + ((size_t)N * 4 + 16) + (size_t)E * 4;

    const int gemm_grid  = (N + 63) / 64;
    const int ntiles128  = (N + 127) / 128;

    if (ws_size >= needed_mfma) {
        hipMemsetAsync(cnt, 0, (size_t)N * 4, stream);
        hipMemsetAsync(bumpBlk, 0, 1024, stream);
        k_count_slot<<<(E + 255) / 256, 256, 0, stream>>>(dst, cnt, slot, E);
        k_dinv2<<<(N + 255) / 256, 256, 0, stream>>>(cnt, dinv, N);
        k_alloc<<<(N + 255) / 256, 256, 0, stream>>>(cnt, row_ptr, bump, N);
        k_fill3<<<(E + 255) / 256, 256, 0, stream>>>(src, dst, row_ptr, slot, col, E);
        k_hist<<<(N + 255) / 256, 256, 0, stream>>>(cnt, hist, N);
        k_scan<<<1, 64, 0, stream>>>(hist, binBase);
        k_sortscatter<<<(N + 255) / 256, 256, 0, stream>>>(cnt, binBase, binCursor, perm, N);

        k_wpack4<<<dim3(8, 4), 256, 0, stream>>>(Ws1, Wt1, Ws2, Wt2, wpk);
        unsigned short* W1pk = wpk;
        unsigned short* W2pk = wpk + 2 * 16384;

        const int n8 = N * DIMS / 8;
        k_cast<<<(n8 + 255) / 256, 256, 0, stream>>>(x_guide, xb, n8);

        const int gather_grid = (N * 16 + 255) / 256;
        // ---- stage 1 ----
        k_gather_b4<<<gather_grid, 256, 0, stream>>>(xb, dinv, row_ptr, cnt, col, perm, aggb, N);
        k_mfma_couple4<<<ntiles128, 512, 0, stream>>>(aggb, W1pk, bs1, bt1, x_main,
                                                      out_main, xb, N, ntiles128);
        // ---- stage 2 ----
        k_gather_b4<<<gather_grid, 256, 0, stream>>>(xb, dinv, row_ptr, cnt, col, perm, aggb, N);
        k_mfma_couple4<<<ntiles128, 512, 0, stream>>>(aggb, W2pk, bs2, bt2, x_guide,
                                                      out_guide, nullptr, N, ntiles128);
    } else if (ws_size >= needed_f32) {
        float* agg = out_guide;
        hipMemsetAsync(cnt, 0, (size_t)N * 4, stream);
        hipMemsetAsync(bumpBlk, 0, 1024, stream);
        hipMemsetAsync(cursor_fb, 0, (size_t)N * 4, stream);
        k_count_slot<<<(E + 255) / 256, 256, 0, stream>>>(dst, cnt, col, E);
        k_dinv2<<<(N + 255) / 256, 256, 0, stream>>>(cnt, dinv, N);
        k_alloc<<<(N + 255) / 256, 256, 0, stream>>>(cnt, row_ptr, bump, N);
        k_fill<<<(E + 255) / 256, 256, 0, stream>>>(src, dst, row_ptr, cursor_fb, dinv, col, wgt_fb, E);
        const int gather_grid32 = (N * 32 + 255) / 256;
        k_gather<<<gather_grid32, 256, 0, stream>>>((const float4*)x_guide, dinv, row_ptr, cnt,
                                                    col, wgt_fb, (float4*)agg, N);
        k_gemm_couple<<<gemm_grid, 256, 0, stream>>>(agg, Ws1, bs1, Wt1, bt1, x_main, out_main, N);
        k_gather<<<gather_grid32, 256, 0, stream>>>((const float4*)out_main, dinv, row_ptr, cnt,
                                                    col, wgt_fb, (float4*)agg, N);
        k_gemm_couple<<<gemm_grid, 256, 0, stream>>>(agg, Ws2, bs2, Wt2, bt2, x_guide, out_guide, N);
    }
}

// Round 8
// 406.615 us; speedup vs baseline: 1.3170x; 1.3170x over previous
//
#include <hip/hip_runtime.h>
#include <cstdint>
#include <cstddef>

constexpr int DIMS = 128;
constexpr int NB = 64;  // degree bins for counting sort (clamped)

typedef __attribute__((ext_vector_type(8))) short bf16x8;
typedef __attribute__((ext_vector_type(8))) unsigned short ushort8v;
typedef __attribute__((ext_vector_type(4))) float f32x4;

__device__ __forceinline__ unsigned short f2b(float f) {
    uint32_t u = __builtin_bit_cast(uint32_t, f);
    uint32_t r = (u + 0x7FFFu + ((u >> 16) & 1u)) >> 16;
    return (unsigned short)r;
}
__device__ __forceinline__ float b2f(unsigned short h) {
    uint32_t u = ((uint32_t)h) << 16;
    return __builtin_bit_cast(float, u);
}

// ---------------- degree + per-edge slot ----------------
__global__ void k_count_slot(const int* __restrict__ dst, int* __restrict__ cnt,
                             int* __restrict__ slot, int E) {
    int e = blockIdx.x * blockDim.x + threadIdx.x;
    if (e < E) slot[e] = atomicAdd(&cnt[dst[e]], 1);
}

// dinv + degree histogram fused (both read cnt)
__global__ void k_dinv2h(const int* __restrict__ cnt, float* __restrict__ dinv,
                         int* __restrict__ hist, int N) {
    __shared__ int h[NB];
    if (threadIdx.x < NB) h[threadIdx.x] = 0;
    __syncthreads();
    int i = blockIdx.x * blockDim.x + threadIdx.x;
    if (i < N) {
        int d = cnt[i];
        dinv[i] = rsqrtf((float)(d + 1));
        if (d > NB - 1) d = NB - 1;
        atomicAdd(&h[d], 1);
    }
    __syncthreads();
    if (threadIdx.x < NB) {
        int v = h[threadIdx.x];
        if (v) atomicAdd(&hist[threadIdx.x], v);
    }
}

// bump-allocated CSR row offsets
__global__ void k_alloc(const int* __restrict__ cnt, int* __restrict__ row_ptr,
                        int* __restrict__ bump, int N) {
    int i = blockIdx.x * blockDim.x + threadIdx.x;
    int lane = threadIdx.x & 63;
    int v = (i < N) ? cnt[i] : 0;
    int x = v;
#pragma unroll
    for (int d = 1; d < 64; d <<= 1) {
        int y = __shfl_up(x, d);
        if (lane >= d) x += y;
    }
    int total = __shfl(x, 63);
    int base = 0;
    if (lane == 0) base = atomicAdd(bump, total);
    base = __shfl(base, 0);
    if (i < N) row_ptr[i] = base + x - v;
}

// atomic-free bucket fill
__global__ void k_fill3(const int* __restrict__ src, const int* __restrict__ dst,
                        const int* __restrict__ row_ptr, const int* __restrict__ slot,
                        int* __restrict__ col, int E) {
    int e = blockIdx.x * blockDim.x + threadIdx.x;
    if (e >= E) return;
    col[row_ptr[dst[e]] + slot[e]] = src[e];
}

// ---------------- counting sort (scan + scatter) ----------------
__global__ void k_scan(const int* __restrict__ hist, int* __restrict__ binBase) {
    int lane = threadIdx.x;  // blockDim.x == 64
    int v = hist[lane];
    int x = v;
#pragma unroll
    for (int d = 1; d < 64; d <<= 1) {
        int y = __shfl_up(x, d);
        if (lane >= d) x += y;
    }
    binBase[lane] = x - v;
}

__global__ void k_sortscatter(const int* __restrict__ cnt, const int* __restrict__ binBase,
                              int* __restrict__ binCursor, int* __restrict__ perm, int N) {
    __shared__ int lh[NB];
    __shared__ int lbase[NB];
    if (threadIdx.x < NB) lh[threadIdx.x] = 0;
    __syncthreads();
    int i = blockIdx.x * blockDim.x + threadIdx.x;
    int d = 0, lr = 0;
    bool valid = (i < N);
    if (valid) {
        d = cnt[i]; if (d > NB - 1) d = NB - 1;
        lr = atomicAdd(&lh[d], 1);
    }
    __syncthreads();
    if (threadIdx.x < NB) {
        int c = lh[threadIdx.x];
        lbase[threadIdx.x] = c ? atomicAdd(&binCursor[threadIdx.x], c) : 0;
    }
    __syncthreads();
    if (valid) perm[binBase[d] + lbase[d] + lr] = i;
}

// ---------------- f32 -> bf16 row cast ----------------
__global__ void k_cast(const float* __restrict__ X, unsigned short* __restrict__ Y, int n8) {
    int i = blockIdx.x * blockDim.x + threadIdx.x;
    if (i >= n8) return;
    const float4* p = (const float4*)X + (size_t)i * 2;
    float4 a = p[0], b = p[1];
    ushort8v o;
    o[0] = f2b(a.x); o[1] = f2b(a.y); o[2] = f2b(a.z); o[3] = f2b(a.w);
    o[4] = f2b(b.x); o[5] = f2b(b.y); o[6] = f2b(b.z); o[7] = f2b(b.w);
    *(ushort8v*)&Y[(size_t)i * 8] = o;
}

// ---------------- W pack (all 4 weights, one launch) ----------------
__global__ void k_wpack4(const float* __restrict__ W0, const float* __restrict__ W1,
                         const float* __restrict__ W2, const float* __restrict__ W3,
                         unsigned short* __restrict__ out) {
    int t = blockIdx.x * blockDim.x + threadIdx.x;  // 0..2047
    if (t >= 2048) return;
    const float* W = (blockIdx.y == 0) ? W0 : (blockIdx.y == 1) ? W1
                   : (blockIdx.y == 2) ? W2 : W3;
    unsigned short* o = out + (size_t)blockIdx.y * 16384;
    int lane = t & 63;
    int nt = (t >> 6) & 7;
    int kk = t >> 9;
    int n = nt * 16 + (lane & 15);
    int k0 = kk * 32 + (lane >> 4) * 8;
    ushort8v h8;
#pragma unroll
    for (int j = 0; j < 8; ++j) h8[j] = f2b(W[(size_t)(k0 + j) * DIMS + n]);
    *(ushort8v*)&o[(size_t)t * 8] = h8;
}

// ---------------- gather, degree-sorted, 16 lanes/node, 4-deep ILP ----------------
__global__ __launch_bounds__(256) void k_gather_b5(
    const unsigned short* __restrict__ Xb, const float* __restrict__ dinv,
    const int* __restrict__ row_ptr, const int* __restrict__ cnt,
    const int* __restrict__ col, const int* __restrict__ perm,
    unsigned short* __restrict__ aggb, int N)
{
    int t = blockIdx.x * blockDim.x + threadIdx.x;
    int g = t >> 4;
    if (g >= N) return;
    const int node = perm[g];
    const size_t base = (size_t)(t & 15) * 8;

    float ds = dinv[node];
    float w0 = ds * ds;
    ushort8v sv = *(const ushort8v*)&Xb[(size_t)node * DIMS + base];
    float acc[8];
#pragma unroll
    for (int q = 0; q < 8; ++q) acc[q] = b2f(sv[q]) * w0;

    const int beg = row_ptr[node];
    const int m = cnt[node];
    int j = 0;
    for (; j + 3 < m; j += 4) {                 // 4 rows in flight
        int s0 = col[beg + j],     s1 = col[beg + j + 1];
        int s2 = col[beg + j + 2], s3 = col[beg + j + 3];
        float wA = ds * dinv[s0], wB = ds * dinv[s1];
        float wC = ds * dinv[s2], wD = ds * dinv[s3];
        ushort8v v0 = *(const ushort8v*)&Xb[(size_t)s0 * DIMS + base];
        ushort8v v1 = *(const ushort8v*)&Xb[(size_t)s1 * DIMS + base];
        ushort8v v2 = *(const ushort8v*)&Xb[(size_t)s2 * DIMS + base];
        ushort8v v3 = *(const ushort8v*)&Xb[(size_t)s3 * DIMS + base];
#pragma unroll
        for (int q = 0; q < 8; ++q) acc[q] = fmaf(wA, b2f(v0[q]), acc[q]);
#pragma unroll
        for (int q = 0; q < 8; ++q) acc[q] = fmaf(wB, b2f(v1[q]), acc[q]);
#pragma unroll
        for (int q = 0; q < 8; ++q) acc[q] = fmaf(wC, b2f(v2[q]), acc[q]);
#pragma unroll
        for (int q = 0; q < 8; ++q) acc[q] = fmaf(wD, b2f(v3[q]), acc[q]);
    }
    for (; j < m; ++j) {
        int s0 = col[beg + j];
        float wA = ds * dinv[s0];
        ushort8v v0 = *(const ushort8v*)&Xb[(size_t)s0 * DIMS + base];
#pragma unroll
        for (int q = 0; q < 8; ++q) acc[q] = fmaf(wA, b2f(v0[q]), acc[q]);
    }
    ushort8v o;
#pragma unroll
    for (int q = 0; q < 8; ++q) o[q] = f2b(acc[q]);
    *(ushort8v*)&aggb[(size_t)node * DIMS + base] = o;
}

// ---------------- MFMA dual-GEMM + coupling (round-6 proven shape) ----------------
// 256 thr = 4 waves x 16 rows = 64-row tile; persistent grid; no reg cap beyond 256.
__global__ __launch_bounds__(256) void k_mfma_couple3(
    const unsigned short* __restrict__ Ab, const unsigned short* __restrict__ Wpk,
    const float* __restrict__ bs, const float* __restrict__ bt,
    const float* __restrict__ Xo, float* __restrict__ Out,
    unsigned short* OutB, int N, int ntiles)
{
    __shared__ unsigned short lds[32768];  // 64 KB: Ws frags | Wt frags
    for (int i = threadIdx.x; i < 4096; i += 256)
        *(ushort8v*)&lds[(size_t)i * 8] = *(const ushort8v*)&Wpk[(size_t)i * 8];
    __syncthreads();
    const unsigned short* wsf = lds;
    const unsigned short* wtf = lds + 16384;

    const int wave = threadIdx.x >> 6, lane = threadIdx.x & 63;
    const int rsub = lane & 15;
    const int ksub = (lane >> 4) * 8;
    const int csub = (lane >> 4) * 4;

    for (int tile = blockIdx.x; tile < ntiles; tile += gridDim.x) {
        const int m = tile * 64 + wave * 16 + rsub;
        const int mld = (m < N) ? m : (N - 1);
        const bool valid = (m < N);

        bf16x8 af[4];
#pragma unroll
        for (int kk = 0; kk < 4; ++kk)
            af[kk] = *(const bf16x8*)&Ab[(size_t)mld * DIMS + kk * 32 + ksub];

        f32x4 acc_s[8], acc_t[8];
#pragma unroll
        for (int nt = 0; nt < 8; ++nt) {
            acc_s[nt] = (f32x4){0.f, 0.f, 0.f, 0.f};
            acc_t[nt] = (f32x4){0.f, 0.f, 0.f, 0.f};
        }

#pragma unroll
        for (int kk = 0; kk < 4; ++kk) {
#pragma unroll
            for (int nt = 0; nt < 8; ++nt) {
                const int fi = ((kk * 8 + nt) * 64 + lane) * 8;
                bf16x8 ws = *(const bf16x8*)&wsf[fi];
                bf16x8 wt = *(const bf16x8*)&wtf[fi];
                acc_s[nt] = __builtin_amdgcn_mfma_f32_16x16x32_bf16(ws, af[kk], acc_s[nt], 0, 0, 0);
                acc_t[nt] = __builtin_amdgcn_mfma_f32_16x16x32_bf16(wt, af[kk], acc_t[nt], 0, 0, 0);
            }
        }

        if (valid) {
#pragma unroll
            for (int nt = 0; nt < 8; ++nt) {
                const int c4 = nt * 16 + csub;
                float4 bsv = *(const float4*)&bs[c4];
                float4 btv = *(const float4*)&bt[c4];
                float4 xo  = *(const float4*)&Xo[(size_t)m * DIMS + c4];
                float4 o;
                o.x = xo.x * expf(tanhf(acc_s[nt][0] + bsv.x)) + (acc_t[nt][0] + btv.x);
                o.y = xo.y * expf(tanhf(acc_s[nt][1] + bsv.y)) + (acc_t[nt][1] + btv.y);
                o.z = xo.z * expf(tanhf(acc_s[nt][2] + bsv.z)) + (acc_t[nt][2] + btv.z);
                o.w = xo.w * expf(tanhf(acc_s[nt][3] + bsv.w)) + (acc_t[nt][3] + btv.w);
                *(float4*)&Out[(size_t)m * DIMS + c4] = o;
                if (OutB) {
                    ushort4 ob;
                    ob.x = f2b(o.x); ob.y = f2b(o.y); ob.z = f2b(o.z); ob.w = f2b(o.w);
                    *(ushort4*)&OutB[(size_t)m * DIMS + c4] = ob;
                }
            }
        }
    }
}

// ---------------- f32 fallback kernels ----------------
__global__ void k_fill(const int* __restrict__ src, const int* __restrict__ dst,
                       const int* __restrict__ row_ptr, int* __restrict__ cursor,
                       const float* __restrict__ dinv,
                       int* __restrict__ col, float* __restrict__ wgt, int E) {
    int e = blockIdx.x * blockDim.x + threadIdx.x;
    if (e >= E) return;
    int s = src[e], d = dst[e];
    int pos = row_ptr[d] + atomicAdd(&cursor[d], 1);
    col[pos] = s;
    wgt[pos] = dinv[s] * dinv[d];
}

__global__ __launch_bounds__(256) void k_gather(
    const float4* __restrict__ X4, const float* __restrict__ dinv,
    const int* __restrict__ row_ptr, const int* __restrict__ cnt,
    const int* __restrict__ col, const float* __restrict__ wgt,
    float4* __restrict__ agg4, int N)
{
    int t = blockIdx.x * blockDim.x + threadIdx.x;
    int node = t >> 5;
    if (node >= N) return;
    int lane = t & 31;
    float ds = dinv[node];
    float w0 = ds * ds;
    float4 acc = X4[(size_t)node * 32 + lane];
    acc.x *= w0; acc.y *= w0; acc.z *= w0; acc.w *= w0;
    int beg = row_ptr[node];
    int m = cnt[node];
    for (int j = 0; j < m; ++j) {
        int s0 = col[beg + j];
        float wa = wgt[beg + j];
        float4 v0 = X4[(size_t)s0 * 32 + lane];
        acc.x = fmaf(wa, v0.x, acc.x); acc.y = fmaf(wa, v0.y, acc.y);
        acc.z = fmaf(wa, v0.z, acc.z); acc.w = fmaf(wa, v0.w, acc.w);
    }
    agg4[(size_t)node * 32 + lane] = acc;
}

__global__ __launch_bounds__(256) void k_gemm_couple(
    const float* A, const float* __restrict__ Ws, const float* __restrict__ bs,
    const float* __restrict__ Wt, const float* __restrict__ bt,
    const float* __restrict__ Xo, float* Out, int N)
{
    constexpr int TM = 64, TK = 16;
    __shared__ float As[TK][TM + 4];
    __shared__ float Ss[TK][DIMS];
    __shared__ float St[TK][DIMS];
    const int tid = threadIdx.x;
    const int ty = tid >> 4, tx = tid & 15;
    const int r0 = ty * 4, c0 = tx * 8;
    const int block_row = blockIdx.x * TM;

    float acc_s[4][8], acc_t[4][8];
#pragma unroll
    for (int r = 0; r < 4; ++r)
#pragma unroll
        for (int c = 0; c < 8; ++c) { acc_s[r][c] = 0.f; acc_t[r][c] = 0.f; }

    const int ar = tid >> 2;
    const int aq = tid & 3;
    int arow = block_row + ar;
    if (arow >= N) arow = N - 1;

    for (int k0 = 0; k0 < DIMS; k0 += TK) {
        __syncthreads();
        {
            float4 v = *(const float4*)&A[(size_t)arow * DIMS + k0 + aq * 4];
            As[aq * 4 + 0][ar] = v.x;
            As[aq * 4 + 1][ar] = v.y;
            As[aq * 4 + 2][ar] = v.z;
            As[aq * 4 + 3][ar] = v.w;
        }
#pragma unroll
        for (int i = 0; i < 2; ++i) {
            int idx = tid + i * 256;
            int kk = idx >> 5;
            int j4 = idx & 31;
            *(float4*)&Ss[kk][j4 * 4] = *(const float4*)&Ws[(size_t)(k0 + kk) * DIMS + j4 * 4];
            *(float4*)&St[kk][j4 * 4] = *(const float4*)&Wt[(size_t)(k0 + kk) * DIMS + j4 * 4];
        }
        __syncthreads();
#pragma unroll
        for (int k = 0; k < TK; ++k) {
            float4 av = *(const float4*)&As[k][r0];
            float a[4] = {av.x, av.y, av.z, av.w};
            float ws8[8], wt8[8];
            *(float4*)&ws8[0] = *(const float4*)&Ss[k][c0];
            *(float4*)&ws8[4] = *(const float4*)&Ss[k][c0 + 4];
            *(float4*)&wt8[0] = *(const float4*)&St[k][c0];
            *(float4*)&wt8[4] = *(const float4*)&St[k][c0 + 4];
#pragma unroll
            for (int r = 0; r < 4; ++r)
#pragma unroll
                for (int c = 0; c < 8; ++c) {
                    acc_s[r][c] = fmaf(a[r], ws8[c], acc_s[r][c]);
                    acc_t[r][c] = fmaf(a[r], wt8[c], acc_t[r][c]);
                }
        }
    }

    float bsv[8], btv[8];
    *(float4*)&bsv[0] = *(const float4*)&bs[c0];
    *(float4*)&bsv[4] = *(const float4*)&bs[c0 + 4];
    *(float4*)&btv[0] = *(const float4*)&bt[c0];
    *(float4*)&btv[4] = *(const float4*)&bt[c0 + 4];
#pragma unroll
    for (int r = 0; r < 4; ++r) {
        int row = block_row + r0 + r;
        if (row < N) {
            float xo[8];
            *(float4*)&xo[0] = *(const float4*)&Xo[(size_t)row * DIMS + c0];
            *(float4*)&xo[4] = *(const float4*)&Xo[(size_t)row * DIMS + c0 + 4];
            float o[8];
#pragma unroll
            for (int c = 0; c < 8; ++c) {
                float s = tanhf(acc_s[r][c] + bsv[c]);
                float t = acc_t[r][c] + btv[c];
                o[c] = xo[c] * expf(s) + t;
            }
            *(float4*)&Out[(size_t)row * DIMS + c0] = *(const float4*)&o[0];
            *(float4*)&Out[(size_t)row * DIMS + c0 + 4] = *(const float4*)&o[4];
        }
    }
}

extern "C" void kernel_launch(void* const* d_in, const int* in_sizes, int n_in,
                              void* d_out, int out_size, void* d_ws, size_t ws_size,
                              hipStream_t stream) {
    const float* x_main  = (const float*)d_in[0];
    const float* x_guide = (const float*)d_in[1];
    const int*   ei      = (const int*)d_in[2];
    const float* Ws1 = (const float*)d_in[3];
    const float* bs1 = (const float*)d_in[4];
    const float* Wt1 = (const float*)d_in[5];
    const float* bt1 = (const float*)d_in[6];
    const float* Ws2 = (const float*)d_in[7];
    const float* bs2 = (const float*)d_in[8];
    const float* Wt2 = (const float*)d_in[9];
    const float* bt2 = (const float*)d_in[10];

    const int N = in_sizes[0] / DIMS;
    const int E = in_sizes[2] / 2;
    const int* src = ei;
    const int* dst = ei + E;

    float* out_main  = (float*)d_out;
    float* out_guide = out_main + (size_t)N * DIMS;

    // ---- ws layout ----
    char* w = (char*)d_ws;
    size_t off = 0;
    auto alloc = [&](size_t bytes) { size_t o = off; off = (off + bytes + 15) & ~(size_t)15; return o; };
    int*   cnt      = (int*)(w + alloc((size_t)N * 4));
    int*   row_ptr  = (int*)(w + alloc((size_t)N * 4));
    int*   bumpBlk  = (int*)(w + alloc(1024));   // bump | hist[64] | binCursor[64]
    int*   bump      = bumpBlk;
    int*   hist      = bumpBlk + 64;
    int*   binCursor = bumpBlk + 128;
    int*   binBase  = (int*)(w + alloc(256));
    float* dinv     = (float*)(w + alloc((size_t)N * 4));
    int*   col      = (int*)(w + alloc((size_t)E * 4));
    int*   perm     = (int*)(w + alloc((size_t)N * 4));
    size_t base_end = off;
    unsigned short* xb   = (unsigned short*)(w + alloc((size_t)N * DIMS * 2));
    unsigned short* aggb = (unsigned short*)(w + alloc((size_t)N * DIMS * 2));
    unsigned short* wpk  = (unsigned short*)(w + alloc((size_t)4 * 16384 * 2));
    size_t needed_mfma = off;
    int* slot = (int*)aggb;   // aliases aggb, consumed before gather writes aggb
    int*   cursor_fb = (int*)(w + base_end);
    float* wgt_fb    = (float*)(w + base_end + (((size_t)N * 4 + 15) & ~(size_t)15));
    size_t needed_f32 = base_end + ((size_t)N * 4 + 16) + (size_t)E * 4;

    const int gemm_grid  = (N + 63) / 64;
    const int ntiles64   = (N + 63) / 64;
    const int mfma_grid  = (ntiles64 < 512) ? ntiles64 : 512;

    if (ws_size >= needed_mfma) {
        hipMemsetAsync(cnt, 0, (size_t)N * 4, stream);
        hipMemsetAsync(bumpBlk, 0, 1024, stream);
        k_count_slot<<<(E + 255) / 256, 256, 0, stream>>>(dst, cnt, slot, E);
        k_dinv2h<<<(N + 255) / 256, 256, 0, stream>>>(cnt, dinv, hist, N);
        k_alloc<<<(N + 255) / 256, 256, 0, stream>>>(cnt, row_ptr, bump, N);
        k_fill3<<<(E + 255) / 256, 256, 0, stream>>>(src, dst, row_ptr, slot, col, E);
        k_scan<<<1, 64, 0, stream>>>(hist, binBase);
        k_sortscatter<<<(N + 255) / 256, 256, 0, stream>>>(cnt, binBase, binCursor, perm, N);

        k_wpack4<<<dim3(8, 4), 256, 0, stream>>>(Ws1, Wt1, Ws2, Wt2, wpk);
        unsigned short* W1pk = wpk;
        unsigned short* W2pk = wpk + 2 * 16384;

        const int n8 = N * DIMS / 8;
        k_cast<<<(n8 + 255) / 256, 256, 0, stream>>>(x_guide, xb, n8);

        const int gather_grid = (N * 16 + 255) / 256;
        // ---- stage 1 ----
        k_gather_b5<<<gather_grid, 256, 0, stream>>>(xb, dinv, row_ptr, cnt, col, perm, aggb, N);
        k_mfma_couple3<<<mfma_grid, 256, 0, stream>>>(aggb, W1pk, bs1, bt1, x_main,
                                                      out_main, xb, N, ntiles64);
        // ---- stage 2 ----
        k_gather_b5<<<gather_grid, 256, 0, stream>>>(xb, dinv, row_ptr, cnt, col, perm, aggb, N);
        k_mfma_couple3<<<mfma_grid, 256, 0, stream>>>(aggb, W2pk, bs2, bt2, x_guide,
                                                      out_guide, nullptr, N, ntiles64);
    } else if (ws_size >= needed_f32) {
        float* agg = out_guide;
        hipMemsetAsync(cnt, 0, (size_t)N * 4, stream);
        hipMemsetAsync(bumpBlk, 0, 1024, stream);
        hipMemsetAsync(cursor_fb, 0, (size_t)N * 4, stream);
        k_count_slot<<<(E + 255) / 256, 256, 0, stream>>>(dst, cnt, col, E);
        k_dinv2h<<<(N + 255) / 256, 256, 0, stream>>>(cnt, dinv, hist, N);
        k_alloc<<<(N + 255) / 256, 256, 0, stream>>>(cnt, row_ptr, bump, N);
        k_fill<<<(E + 255) / 256, 256, 0, stream>>>(src, dst, row_ptr, cursor_fb, dinv, col, wgt_fb, E);
        const int gather_grid32 = (N * 32 + 255) / 256;
        k_gather<<<gather_grid32, 256, 0, stream>>>((const float4*)x_guide, dinv, row_ptr, cnt,
                                                    col, wgt_fb, (float4*)agg, N);
        k_gemm_couple<<<gemm_grid, 256, 0, stream>>>(agg, Ws1, bs1, Wt1, bt1, x_main, out_main, N);
        k_gather<<<gather_grid32, 256, 0, stream>>>((const float4*)out_main, dinv, row_ptr, cnt,
                                                    col, wgt_fb, (float4*)agg, N);
        k_gemm_couple<<<gemm_grid, 256, 0, stream>>>(agg, Ws2, bs2, Wt2, bt2, x_guide, out_guide, N);
    }
}

// Round 9
// 382.447 us; speedup vs baseline: 1.4003x; 1.0632x over previous
//
#include <hip/hip_runtime.h>
#include <cstdint>
#include <cstddef>

constexpr int DIMS = 128;
constexpr int NB = 64;  // degree bins for counting sort (clamped)

typedef __attribute__((ext_vector_type(8))) short bf16x8;
typedef __attribute__((ext_vector_type(8))) unsigned short ushort8v;
typedef __attribute__((ext_vector_type(4))) float f32x4;

__device__ __forceinline__ unsigned short f2b(float f) {
    uint32_t u = __builtin_bit_cast(uint32_t, f);
    uint32_t r = (u + 0x7FFFu + ((u >> 16) & 1u)) >> 16;
    return (unsigned short)r;
}
__device__ __forceinline__ float b2f(unsigned short h) {
    uint32_t u = ((uint32_t)h) << 16;
    return __builtin_bit_cast(float, u);
}

// ---------------- degree + per-edge slot ----------------
__global__ void k_count_slot(const int* __restrict__ dst, int* __restrict__ cnt,
                             int* __restrict__ slot, int E) {
    int e = blockIdx.x * blockDim.x + threadIdx.x;
    if (e < E) slot[e] = atomicAdd(&cnt[dst[e]], 1);
}

// dinv + degree histogram fused
__global__ void k_dinv2h(const int* __restrict__ cnt, float* __restrict__ dinv,
                         int* __restrict__ hist, int N) {
    __shared__ int h[NB];
    if (threadIdx.x < NB) h[threadIdx.x] = 0;
    __syncthreads();
    int i = blockIdx.x * blockDim.x + threadIdx.x;
    if (i < N) {
        int d = cnt[i];
        dinv[i] = rsqrtf((float)(d + 1));
        if (d > NB - 1) d = NB - 1;
        atomicAdd(&h[d], 1);
    }
    __syncthreads();
    if (threadIdx.x < NB) {
        int v = h[threadIdx.x];
        if (v) atomicAdd(&hist[threadIdx.x], v);
    }
}

// bump-allocated CSR row offsets
__global__ void k_alloc(const int* __restrict__ cnt, int* __restrict__ row_ptr,
                        int* __restrict__ bump, int N) {
    int i = blockIdx.x * blockDim.x + threadIdx.x;
    int lane = threadIdx.x & 63;
    int v = (i < N) ? cnt[i] : 0;
    int x = v;
#pragma unroll
    for (int d = 1; d < 64; d <<= 1) {
        int y = __shfl_up(x, d);
        if (lane >= d) x += y;
    }
    int total = __shfl(x, 63);
    int base = 0;
    if (lane == 0) base = atomicAdd(bump, total);
    base = __shfl(base, 0);
    if (i < N) row_ptr[i] = base + x - v;
}

// atomic-free bucket fill
__global__ void k_fill3(const int* __restrict__ src, const int* __restrict__ dst,
                        const int* __restrict__ row_ptr, const int* __restrict__ slot,
                        int* __restrict__ col, int E) {
    int e = blockIdx.x * blockDim.x + threadIdx.x;
    if (e >= E) return;
    col[row_ptr[dst[e]] + slot[e]] = src[e];
}

// ---------------- counting sort (scan + scatter) ----------------
__global__ void k_scan(const int* __restrict__ hist, int* __restrict__ binBase) {
    int lane = threadIdx.x;  // blockDim.x == 64
    int v = hist[lane];
    int x = v;
#pragma unroll
    for (int d = 1; d < 64; d <<= 1) {
        int y = __shfl_up(x, d);
        if (lane >= d) x += y;
    }
    binBase[lane] = x - v;
}

__global__ void k_sortscatter(const int* __restrict__ cnt, const int* __restrict__ binBase,
                              int* __restrict__ binCursor, int* __restrict__ perm, int N) {
    __shared__ int lh[NB];
    __shared__ int lbase[NB];
    if (threadIdx.x < NB) lh[threadIdx.x] = 0;
    __syncthreads();
    int i = blockIdx.x * blockDim.x + threadIdx.x;
    int d = 0, lr = 0;
    bool valid = (i < N);
    if (valid) {
        d = cnt[i]; if (d > NB - 1) d = NB - 1;
        lr = atomicAdd(&lh[d], 1);
    }
    __syncthreads();
    if (threadIdx.x < NB) {
        int c = lh[threadIdx.x];
        lbase[threadIdx.x] = c ? atomicAdd(&binCursor[threadIdx.x], c) : 0;
    }
    __syncthreads();
    if (valid) perm[binBase[d] + lbase[d] + lr] = i;
}

// ---------------- f32 -> bf16 row cast ----------------
__global__ void k_cast(const float* __restrict__ X, unsigned short* __restrict__ Y, int n8) {
    int i = blockIdx.x * blockDim.x + threadIdx.x;
    if (i >= n8) return;
    const float4* p = (const float4*)X + (size_t)i * 2;
    float4 a = p[0], b = p[1];
    ushort8v o;
    o[0] = f2b(a.x); o[1] = f2b(a.y); o[2] = f2b(a.z); o[3] = f2b(a.w);
    o[4] = f2b(b.x); o[5] = f2b(b.y); o[6] = f2b(b.z); o[7] = f2b(b.w);
    *(ushort8v*)&Y[(size_t)i * 8] = o;
}

// ---------------- W pack (all 4 weights, one launch) ----------------
__global__ void k_wpack4(const float* __restrict__ W0, const float* __restrict__ W1,
                         const float* __restrict__ W2, const float* __restrict__ W3,
                         unsigned short* __restrict__ out) {
    int t = blockIdx.x * blockDim.x + threadIdx.x;  // 0..2047
    if (t >= 2048) return;
    const float* W = (blockIdx.y == 0) ? W0 : (blockIdx.y == 1) ? W1
                   : (blockIdx.y == 2) ? W2 : W3;
    unsigned short* o = out + (size_t)blockIdx.y * 16384;
    int lane = t & 63;
    int nt = (t >> 6) & 7;
    int kk = t >> 9;
    int n = nt * 16 + (lane & 15);
    int k0 = kk * 32 + (lane >> 4) * 8;
    ushort8v h8;
#pragma unroll
    for (int j = 0; j < 8; ++j) h8[j] = f2b(W[(size_t)(k0 + j) * DIMS + n]);
    *(ushort8v*)&o[(size_t)t * 8] = h8;
}

// ---------------- gather, degree-sorted, 16 lanes/node, 4-deep ILP ----------------
__global__ __launch_bounds__(256) void k_gather_b5(
    const unsigned short* __restrict__ Xb, const float* __restrict__ dinv,
    const int* __restrict__ row_ptr, const int* __restrict__ cnt,
    const int* __restrict__ col, const int* __restrict__ perm,
    unsigned short* __restrict__ aggb, int N)
{
    int t = blockIdx.x * blockDim.x + threadIdx.x;
    int g = t >> 4;
    if (g >= N) return;
    const int node = perm[g];
    const size_t base = (size_t)(t & 15) * 8;

    float ds = dinv[node];
    float w0 = ds * ds;
    ushort8v sv = *(const ushort8v*)&Xb[(size_t)node * DIMS + base];
    float acc[8];
#pragma unroll
    for (int q = 0; q < 8; ++q) acc[q] = b2f(sv[q]) * w0;

    const int beg = row_ptr[node];
    const int m = cnt[node];
    int j = 0;
    for (; j + 3 < m; j += 4) {
        int s0 = col[beg + j],     s1 = col[beg + j + 1];
        int s2 = col[beg + j + 2], s3 = col[beg + j + 3];
        float wA = ds * dinv[s0], wB = ds * dinv[s1];
        float wC = ds * dinv[s2], wD = ds * dinv[s3];
        ushort8v v0 = *(const ushort8v*)&Xb[(size_t)s0 * DIMS + base];
        ushort8v v1 = *(const ushort8v*)&Xb[(size_t)s1 * DIMS + base];
        ushort8v v2 = *(const ushort8v*)&Xb[(size_t)s2 * DIMS + base];
        ushort8v v3 = *(const ushort8v*)&Xb[(size_t)s3 * DIMS + base];
#pragma unroll
        for (int q = 0; q < 8; ++q) acc[q] = fmaf(wA, b2f(v0[q]), acc[q]);
#pragma unroll
        for (int q = 0; q < 8; ++q) acc[q] = fmaf(wB, b2f(v1[q]), acc[q]);
#pragma unroll
        for (int q = 0; q < 8; ++q) acc[q] = fmaf(wC, b2f(v2[q]), acc[q]);
#pragma unroll
        for (int q = 0; q < 8; ++q) acc[q] = fmaf(wD, b2f(v3[q]), acc[q]);
    }
    for (; j < m; ++j) {
        int s0 = col[beg + j];
        float wA = ds * dinv[s0];
        ushort8v v0 = *(const ushort8v*)&Xb[(size_t)s0 * DIMS + base];
#pragma unroll
        for (int q = 0; q < 8; ++q) acc[q] = fmaf(wA, b2f(v0[q]), acc[q]);
    }
    ushort8v o;
#pragma unroll
    for (int q = 0; q < 8; ++q) o[q] = f2b(acc[q]);
    *(ushort8v*)&aggb[(size_t)node * DIMS + base] = o;
}

// ---------------- MFMA dual-GEMM + coupling, v5: column-half blocks, 32KB LDS ----------------
// Block handles 64 rows x 64 cols (half h of the 128 cols). LDS = half of Ws|Wt frags.
// idx = tile*2 + h, grid-stride over 2*ntiles.
__global__ __launch_bounds__(256) void k_mfma_couple5(
    const unsigned short* __restrict__ Ab, const unsigned short* __restrict__ Wpk,
    const float* __restrict__ bs, const float* __restrict__ bt,
    const float* __restrict__ Xo, float* __restrict__ Out,
    unsigned short* OutB, int N, int nidx)
{
    __shared__ unsigned short lds[16384];  // 32 KB: Ws half | Wt half

    const int wave = threadIdx.x >> 6, lane = threadIdx.x & 63;
    const int rsub = lane & 15;
    const int ksub = (lane >> 4) * 8;
    const int csub = (lane >> 4) * 4;

    const int h = blockIdx.x & 1;  // column half (same for all idx this block touches)

    // stage half of Ws and half of Wt: 2048 frag-rows of 8 ushorts
    for (int i = threadIdx.x; i < 2048; i += 256) {
        int wsel = i >> 10;             // 0 = Ws, 1 = Wt
        int rem = i & 1023;             // kk(2b) | ntl(2b) | lane(6b)
        int kk = rem >> 8;
        int ntl = (rem >> 6) & 3;
        int ln = rem & 63;
        int gfrag = (kk * 8 + h * 4 + ntl) * 64 + ln;   // index in full W frag array
        *(ushort8v*)&lds[(size_t)i * 8] =
            *(const ushort8v*)&Wpk[((size_t)wsel * 16384) + (size_t)gfrag * 8];
    }
    __syncthreads();
    const unsigned short* wsf = lds;            // 1024 frag-rows
    const unsigned short* wtf = lds + 8192;     // 1024 frag-rows

    for (int idx = blockIdx.x; idx < nidx; idx += gridDim.x) {
        const int tile = idx >> 1;     // idx&1 == h always (gridDim.x even)
        const int m = tile * 64 + wave * 16 + rsub;
        const int mld = (m < N) ? m : (N - 1);
        const bool valid = (m < N);

        bf16x8 af[4];
#pragma unroll
        for (int kk = 0; kk < 4; ++kk)
            af[kk] = *(const bf16x8*)&Ab[(size_t)mld * DIMS + kk * 32 + ksub];

        f32x4 acc_s[4], acc_t[4];
#pragma unroll
        for (int nt = 0; nt < 4; ++nt) {
            acc_s[nt] = (f32x4){0.f, 0.f, 0.f, 0.f};
            acc_t[nt] = (f32x4){0.f, 0.f, 0.f, 0.f};
        }

#pragma unroll
        for (int kk = 0; kk < 4; ++kk) {
#pragma unroll
            for (int nt = 0; nt < 4; ++nt) {
                const int fi = ((kk * 4 + nt) * 64 + lane) * 8;
                bf16x8 ws = *(const bf16x8*)&wsf[fi];
                bf16x8 wt = *(const bf16x8*)&wtf[fi];
                acc_s[nt] = __builtin_amdgcn_mfma_f32_16x16x32_bf16(ws, af[kk], acc_s[nt], 0, 0, 0);
                acc_t[nt] = __builtin_amdgcn_mfma_f32_16x16x32_bf16(wt, af[kk], acc_t[nt], 0, 0, 0);
            }
        }

        if (valid) {
#pragma unroll
            for (int nt = 0; nt < 4; ++nt) {
                const int c4 = (h * 4 + nt) * 16 + csub;
                float4 bsv = *(const float4*)&bs[c4];
                float4 btv = *(const float4*)&bt[c4];
                float4 xo  = *(const float4*)&Xo[(size_t)m * DIMS + c4];
                float4 o;
                o.x = xo.x * expf(tanhf(acc_s[nt][0] + bsv.x)) + (acc_t[nt][0] + btv.x);
                o.y = xo.y * expf(tanhf(acc_s[nt][1] + bsv.y)) + (acc_t[nt][1] + btv.y);
                o.z = xo.z * expf(tanhf(acc_s[nt][2] + bsv.z)) + (acc_t[nt][2] + btv.z);
                o.w = xo.w * expf(tanhf(acc_s[nt][3] + bsv.w)) + (acc_t[nt][3] + btv.w);
                *(float4*)&Out[(size_t)m * DIMS + c4] = o;
                if (OutB) {
                    ushort4 ob;
                    ob.x = f2b(o.x); ob.y = f2b(o.y); ob.z = f2b(o.z); ob.w = f2b(o.w);
                    *(ushort4*)&OutB[(size_t)m * DIMS + c4] = ob;
                }
            }
        }
    }
}

// ---------------- f32 fallback kernels ----------------
__global__ void k_fill(const int* __restrict__ src, const int* __restrict__ dst,
                       const int* __restrict__ row_ptr, int* __restrict__ cursor,
                       const float* __restrict__ dinv,
                       int* __restrict__ col, float* __restrict__ wgt, int E) {
    int e = blockIdx.x * blockDim.x + threadIdx.x;
    if (e >= E) return;
    int s = src[e], d = dst[e];
    int pos = row_ptr[d] + atomicAdd(&cursor[d], 1);
    col[pos] = s;
    wgt[pos] = dinv[s] * dinv[d];
}

__global__ __launch_bounds__(256) void k_gather(
    const float4* __restrict__ X4, const float* __restrict__ dinv,
    const int* __restrict__ row_ptr, const int* __restrict__ cnt,
    const int* __restrict__ col, const float* __restrict__ wgt,
    float4* __restrict__ agg4, int N)
{
    int t = blockIdx.x * blockDim.x + threadIdx.x;
    int node = t >> 5;
    if (node >= N) return;
    int lane = t & 31;
    float ds = dinv[node];
    float w0 = ds * ds;
    float4 acc = X4[(size_t)node * 32 + lane];
    acc.x *= w0; acc.y *= w0; acc.z *= w0; acc.w *= w0;
    int beg = row_ptr[node];
    int m = cnt[node];
    for (int j = 0; j < m; ++j) {
        int s0 = col[beg + j];
        float wa = wgt[beg + j];
        float4 v0 = X4[(size_t)s0 * 32 + lane];
        acc.x = fmaf(wa, v0.x, acc.x); acc.y = fmaf(wa, v0.y, acc.y);
        acc.z = fmaf(wa, v0.z, acc.z); acc.w = fmaf(wa, v0.w, acc.w);
    }
    agg4[(size_t)node * 32 + lane] = acc;
}

__global__ __launch_bounds__(256) void k_gemm_couple(
    const float* A, const float* __restrict__ Ws, const float* __restrict__ bs,
    const float* __restrict__ Wt, const float* __restrict__ bt,
    const float* __restrict__ Xo, float* Out, int N)
{
    constexpr int TM = 64, TK = 16;
    __shared__ float As[TK][TM + 4];
    __shared__ float Ss[TK][DIMS];
    __shared__ float St[TK][DIMS];
    const int tid = threadIdx.x;
    const int ty = tid >> 4, tx = tid & 15;
    const int r0 = ty * 4, c0 = tx * 8;
    const int block_row = blockIdx.x * TM;

    float acc_s[4][8], acc_t[4][8];
#pragma unroll
    for (int r = 0; r < 4; ++r)
#pragma unroll
        for (int c = 0; c < 8; ++c) { acc_s[r][c] = 0.f; acc_t[r][c] = 0.f; }

    const int ar = tid >> 2;
    const int aq = tid & 3;
    int arow = block_row + ar;
    if (arow >= N) arow = N - 1;

    for (int k0 = 0; k0 < DIMS; k0 += TK) {
        __syncthreads();
        {
            float4 v = *(const float4*)&A[(size_t)arow * DIMS + k0 + aq * 4];
            As[aq * 4 + 0][ar] = v.x;
            As[aq * 4 + 1][ar] = v.y;
            As[aq * 4 + 2][ar] = v.z;
            As[aq * 4 + 3][ar] = v.w;
        }
#pragma unroll
        for (int i = 0; i < 2; ++i) {
            int idx = tid + i * 256;
            int kk = idx >> 5;
            int j4 = idx & 31;
            *(float4*)&Ss[kk][j4 * 4] = *(const float4*)&Ws[(size_t)(k0 + kk) * DIMS + j4 * 4];
            *(float4*)&St[kk][j4 * 4] = *(const float4*)&Wt[(size_t)(k0 + kk) * DIMS + j4 * 4];
        }
        __syncthreads();
#pragma unroll
        for (int k = 0; k < TK; ++k) {
            float4 av = *(const float4*)&As[k][r0];
            float a[4] = {av.x, av.y, av.z, av.w};
            float ws8[8], wt8[8];
            *(float4*)&ws8[0] = *(const float4*)&Ss[k][c0];
            *(float4*)&ws8[4] = *(const float4*)&Ss[k][c0 + 4];
            *(float4*)&wt8[0] = *(const float4*)&St[k][c0];
            *(float4*)&wt8[4] = *(const float4*)&St[k][c0 + 4];
#pragma unroll
            for (int r = 0; r < 4; ++r)
#pragma unroll
                for (int c = 0; c < 8; ++c) {
                    acc_s[r][c] = fmaf(a[r], ws8[c], acc_s[r][c]);
                    acc_t[r][c] = fmaf(a[r], wt8[c], acc_t[r][c]);
                }
        }
    }

    float bsv[8], btv[8];
    *(float4*)&bsv[0] = *(const float4*)&bs[c0];
    *(float4*)&bsv[4] = *(const float4*)&bs[c0 + 4];
    *(float4*)&btv[0] = *(const float4*)&bt[c0];
    *(float4*)&btv[4] = *(const float4*)&bt[c0 + 4];
#pragma unroll
    for (int r = 0; r < 4; ++r) {
        int row = block_row + r0 + r;
        if (row < N) {
            float xo[8];
            *(float4*)&xo[0] = *(const float4*)&Xo[(size_t)row * DIMS + c0];
            *(float4*)&xo[4] = *(const float4*)&Xo[(size_t)row * DIMS + c0 + 4];
            float o[8];
#pragma unroll
            for (int c = 0; c < 8; ++c) {
                float s = tanhf(acc_s[r][c] + bsv[c]);
                float t = acc_t[r][c] + btv[c];
                o[c] = xo[c] * expf(s) + t;
            }
            *(float4*)&Out[(size_t)row * DIMS + c0] = *(const float4*)&o[0];
            *(float4*)&Out[(size_t)row * DIMS + c0 + 4] = *(const float4*)&o[4];
        }
    }
}

extern "C" void kernel_launch(void* const* d_in, const int* in_sizes, int n_in,
                              void* d_out, int out_size, void* d_ws, size_t ws_size,
                              hipStream_t stream) {
    const float* x_main  = (const float*)d_in[0];
    const float* x_guide = (const float*)d_in[1];
    const int*   ei      = (const int*)d_in[2];
    const float* Ws1 = (const float*)d_in[3];
    const float* bs1 = (const float*)d_in[4];
    const float* Wt1 = (const float*)d_in[5];
    const float* bt1 = (const float*)d_in[6];
    const float* Ws2 = (const float*)d_in[7];
    const float* bs2 = (const float*)d_in[8];
    const float* Wt2 = (const float*)d_in[9];
    const float* bt2 = (const float*)d_in[10];

    const int N = in_sizes[0] / DIMS;
    const int E = in_sizes[2] / 2;
    const int* src = ei;
    const int* dst = ei + E;

    float* out_main  = (float*)d_out;
    float* out_guide = out_main + (size_t)N * DIMS;

    // ---- ws layout ----
    char* w = (char*)d_ws;
    size_t off = 0;
    auto alloc = [&](size_t bytes) { size_t o = off; off = (off + bytes + 15) & ~(size_t)15; return o; };
    int*   cnt      = (int*)(w + alloc((size_t)N * 4));
    int*   row_ptr  = (int*)(w + alloc((size_t)N * 4));
    int*   bumpBlk  = (int*)(w + alloc(1024));   // bump | hist[64] | binCursor[64]
    int*   bump      = bumpBlk;
    int*   hist      = bumpBlk + 64;
    int*   binCursor = bumpBlk + 128;
    int*   binBase  = (int*)(w + alloc(256));
    float* dinv     = (float*)(w + alloc((size_t)N * 4));
    int*   col      = (int*)(w + alloc((size_t)E * 4));
    int*   perm     = (int*)(w + alloc((size_t)N * 4));
    size_t base_end = off;
    unsigned short* xb   = (unsigned short*)(w + alloc((size_t)N * DIMS * 2));
    unsigned short* aggb = (unsigned short*)(w + alloc((size_t)N * DIMS * 2));
    unsigned short* wpk  = (unsigned short*)(w + alloc((size_t)4 * 16384 * 2));
    size_t needed_mfma = off;
    int* slot = (int*)aggb;   // aliases aggb, consumed before gather writes aggb
    int*   cursor_fb = (int*)(w + base_end);
    float* wgt_fb    = (float*)(w + base_end + (((size_t)N * 4 + 15) & ~(size_t)15));
    size_t needed_f32 = base_end + ((size_t)N * 4 + 16) + (size_t)E * 4;

    const int gemm_grid  = (N + 63) / 64;
    const int ntiles64   = (N + 63) / 64;
    const int nidx       = ntiles64 * 2;
    int mfma_grid        = (nidx < 1024) ? nidx : 1024;
    mfma_grid            = (mfma_grid + 1) & ~1;   // keep even so h is loop-invariant

    if (ws_size >= needed_mfma) {
        hipMemsetAsync(cnt, 0, (size_t)N * 4, stream);
        hipMemsetAsync(bumpBlk, 0, 1024, stream);
        k_count_slot<<<(E + 255) / 256, 256, 0, stream>>>(dst, cnt, slot, E);
        k_dinv2h<<<(N + 255) / 256, 256, 0, stream>>>(cnt, dinv, hist, N);
        k_alloc<<<(N + 255) / 256, 256, 0, stream>>>(cnt, row_ptr, bump, N);
        k_fill3<<<(E + 255) / 256, 256, 0, stream>>>(src, dst, row_ptr, slot, col, E);
        k_scan<<<1, 64, 0, stream>>>(hist, binBase);
        k_sortscatter<<<(N + 255) / 256, 256, 0, stream>>>(cnt, binBase, binCursor, perm, N);

        k_wpack4<<<dim3(8, 4), 256, 0, stream>>>(Ws1, Wt1, Ws2, Wt2, wpk);
        unsigned short* W1pk = wpk;
        unsigned short* W2pk = wpk + 2 * 16384;

        const int n8 = N * DIMS / 8;
        k_cast<<<(n8 + 255) / 256, 256, 0, stream>>>(x_guide, xb, n8);

        const int gather_grid = (N * 16 + 255) / 256;
        // ---- stage 1 ----
        k_gather_b5<<<gather_grid, 256, 0, stream>>>(xb, dinv, row_ptr, cnt, col, perm, aggb, N);
        k_mfma_couple5<<<mfma_grid, 256, 0, stream>>>(aggb, W1pk, bs1, bt1, x_main,
                                                      out_main, xb, N, nidx);
        // ---- stage 2 ----
        k_gather_b5<<<gather_grid, 256, 0, stream>>>(xb, dinv, row_ptr, cnt, col, perm, aggb, N);
        k_mfma_couple5<<<mfma_grid, 256, 0, stream>>>(aggb, W2pk, bs2, bt2, x_guide,
                                                      out_guide, nullptr, N, nidx);
    } else if (ws_size >= needed_f32) {
        float* agg = out_guide;
        hipMemsetAsync(cnt, 0, (size_t)N * 4, stream);
        hipMemsetAsync(bumpBlk, 0, 1024, stream);
        hipMemsetAsync(cursor_fb, 0, (size_t)N * 4, stream);
        k_count_slot<<<(E + 255) / 256, 256, 0, stream>>>(dst, cnt, col, E);
        k_dinv2h<<<(N + 255) / 256, 256, 0, stream>>>(cnt, dinv, hist, N);
        k_alloc<<<(N + 255) / 256, 256, 0, stream>>>(cnt, row_ptr, bump, N);
        k_fill<<<(E + 255) / 256, 256, 0, stream>>>(src, dst, row_ptr, cursor_fb, dinv, col, wgt_fb, E);
        const int gather_grid32 = (N * 32 + 255) / 256;
        k_gather<<<gather_grid32, 256, 0, stream>>>((const float4*)x_guide, dinv, row_ptr, cnt,
                                                    col, wgt_fb, (float4*)agg, N);
        k_gemm_couple<<<gemm_grid, 256, 0, stream>>>(agg, Ws1, bs1, Wt1, bt1, x_main, out_main, N);
        k_gather<<<gather_grid32, 256, 0, stream>>>((const float4*)out_main, dinv, row_ptr, cnt,
                                                    col, wgt_fb, (float4*)agg, N);
        k_gemm_couple<<<gemm_grid, 256, 0, stream>>>(agg, Ws2, bs2, Wt2, bt2, x_guide, out_guide, N);
    }
}

// Round 10
// 361.761 us; speedup vs baseline: 1.4803x; 1.0572x over previous
//
#include <hip/hip_runtime.h>
#include <cstdint>
#include <cstddef>

constexpr int DIMS = 128;
constexpr int NB = 64;    // degree bins for counting sort (clamped)

typedef __attribute__((ext_vector_type(8))) short bf16x8;
typedef __attribute__((ext_vector_type(8))) unsigned short ushort8v;
typedef __attribute__((ext_vector_type(4))) float f32x4;

__device__ __forceinline__ unsigned short f2b(float f) {
    uint32_t u = __builtin_bit_cast(uint32_t, f);
    uint32_t r = (u + 0x7FFFu + ((u >> 16) & 1u)) >> 16;
    return (unsigned short)r;
}
__device__ __forceinline__ float b2f(unsigned short h) {
    uint32_t u = ((uint32_t)h) << 16;
    return __builtin_bit_cast(float, u);
}

// ================= bucketed CSR build (no slow global atomics) =================
// Coarse buckets of 512 nodes: bucket(d) = d >> 9.  nbkt <= 512 assumed (guarded host-side).

// per-block LDS histogram of coarse buckets -> global (padded stride 16)
__global__ __launch_bounds__(1024) void k_bhist(const int* __restrict__ dst,
                                                int* __restrict__ bktCnt,
                                                int E, int nbkt, int Ec) {
    __shared__ int lh[512];
    if (threadIdx.x < 512) lh[threadIdx.x] = 0;
    __syncthreads();
    int base = blockIdx.x * Ec;
    int end = min(E, base + Ec);
    for (int i = base + threadIdx.x; i < end; i += 1024)
        atomicAdd(&lh[dst[i] >> 9], 1);
    __syncthreads();
    if (threadIdx.x < nbkt) {
        int v = lh[threadIdx.x];
        if (v) atomicAdd(&bktCnt[threadIdx.x * 16], v);
    }
}

// exclusive scan over <=512 coarse buckets (1 wave); init cursors
__global__ void k_bscan(const int* __restrict__ bktCnt, int* __restrict__ bktBase,
                        int* __restrict__ bktCursor, int nbkt, int E) {
    int lane = threadIdx.x;  // blockDim.x == 64
    int v[8]; int s = 0;
#pragma unroll
    for (int k = 0; k < 8; ++k) {
        int idx = lane * 8 + k;
        int c = (idx < nbkt) ? bktCnt[idx * 16] : 0;
        v[k] = s; s += c;
    }
    int x = s;
#pragma unroll
    for (int d = 1; d < 64; d <<= 1) {
        int y = __shfl_up(x, d);
        if (lane >= d) x += y;
    }
    int excl = x - s;
#pragma unroll
    for (int k = 0; k < 8; ++k) {
        int idx = lane * 8 + k;
        if (idx < nbkt) { int bb = excl + v[k]; bktBase[idx] = bb; bktCursor[idx * 16] = bb; }
    }
    if (lane == 0) bktBase[nbkt] = E;
}

// scatter edges into bucketed array; one returning atomic per (block, nonzero bucket)
__global__ __launch_bounds__(1024) void k_bscatter(const int* __restrict__ src,
                                                   const int* __restrict__ dst,
                                                   int* __restrict__ bktCursor,
                                                   int2* __restrict__ einfo,
                                                   int E, int nbkt, int Ec) {
    __shared__ int lh[512];
    __shared__ int lbase[512];
    __shared__ int lcur[512];
    if (threadIdx.x < 512) { lh[threadIdx.x] = 0; lcur[threadIdx.x] = 0; }
    __syncthreads();
    int base = blockIdx.x * Ec;
    int end = min(E, base + Ec);
    for (int i = base + threadIdx.x; i < end; i += 1024)
        atomicAdd(&lh[dst[i] >> 9], 1);
    __syncthreads();
    if (threadIdx.x < nbkt) {
        int c = lh[threadIdx.x];
        lbase[threadIdx.x] = c ? atomicAdd(&bktCursor[threadIdx.x * 16], c) : 0;
    }
    __syncthreads();
    for (int i = base + threadIdx.x; i < end; i += 1024) {
        int d = dst[i], s = src[i];
        int b = d >> 9;
        int r = atomicAdd(&lcur[b], 1);
        einfo[lbase[b] + r] = make_int2(s, d);
    }
}

// per-bucket fine CSR entirely in LDS: count -> scan -> slot scatter; emits cnt/row_ptr/col
__global__ __launch_bounds__(512) void k_bcsr(const int2* __restrict__ einfo,
                                              const int* __restrict__ bktBase,
                                              int* __restrict__ col, int* __restrict__ row_ptr,
                                              int* __restrict__ cnt, int N) {
    __shared__ int lcnt[512];
    __shared__ int loff[512];
    __shared__ int lcur[512];
    const int b = blockIdx.x;
    const int node0 = b << 9;
    lcnt[threadIdx.x] = 0; lcur[threadIdx.x] = 0;
    __syncthreads();
    const int ebeg = bktBase[b], eend = bktBase[b + 1];
    for (int i = ebeg + threadIdx.x; i < eend; i += 512)
        atomicAdd(&lcnt[einfo[i].y & 511], 1);
    __syncthreads();
    if (threadIdx.x < 64) {  // wave 0: exclusive scan of 512
        int lane = threadIdx.x;
        int v[8]; int s = 0;
#pragma unroll
        for (int k = 0; k < 8; ++k) { v[k] = s; s += lcnt[lane * 8 + k]; }
        int x = s;
#pragma unroll
        for (int d = 1; d < 64; d <<= 1) { int y = __shfl_up(x, d); if (lane >= d) x += y; }
        int excl = x - s;
#pragma unroll
        for (int k = 0; k < 8; ++k) loff[lane * 8 + k] = excl + v[k];
    }
    __syncthreads();
    const int node = node0 + threadIdx.x;
    if (node < N) {
        row_ptr[node] = ebeg + loff[threadIdx.x];
        cnt[node] = lcnt[threadIdx.x];
    }
    for (int i = ebeg + threadIdx.x; i < eend; i += 512) {
        int2 e = einfo[i];
        int dl = e.y & 511;
        int r = atomicAdd(&lcur[dl], 1);
        col[ebeg + loff[dl] + r] = e.x;
    }
}

// ================= old-path CSR kernels (fallback) =================
__global__ void k_count_slot(const int* __restrict__ dst, int* __restrict__ cnt,
                             int* __restrict__ slot, int E) {
    int e = blockIdx.x * blockDim.x + threadIdx.x;
    if (e < E) slot[e] = atomicAdd(&cnt[dst[e]], 1);
}

__global__ void k_alloc(const int* __restrict__ cnt, int* __restrict__ row_ptr,
                        int* __restrict__ bump, int N) {
    int i = blockIdx.x * blockDim.x + threadIdx.x;
    int lane = threadIdx.x & 63;
    int v = (i < N) ? cnt[i] : 0;
    int x = v;
#pragma unroll
    for (int d = 1; d < 64; d <<= 1) {
        int y = __shfl_up(x, d);
        if (lane >= d) x += y;
    }
    int total = __shfl(x, 63);
    int base = 0;
    if (lane == 0) base = atomicAdd(bump, total);
    base = __shfl(base, 0);
    if (i < N) row_ptr[i] = base + x - v;
}

__global__ void k_fill3(const int* __restrict__ src, const int* __restrict__ dst,
                        const int* __restrict__ row_ptr, const int* __restrict__ slot,
                        int* __restrict__ col, int E) {
    int e = blockIdx.x * blockDim.x + threadIdx.x;
    if (e >= E) return;
    col[row_ptr[dst[e]] + slot[e]] = src[e];
}

// ================= shared small kernels =================
// dinv + degree histogram fused
__global__ void k_dinv2h(const int* __restrict__ cnt, float* __restrict__ dinv,
                         int* __restrict__ hist, int N) {
    __shared__ int h[NB];
    if (threadIdx.x < NB) h[threadIdx.x] = 0;
    __syncthreads();
    int i = blockIdx.x * blockDim.x + threadIdx.x;
    if (i < N) {
        int d = cnt[i];
        dinv[i] = rsqrtf((float)(d + 1));
        if (d > NB - 1) d = NB - 1;
        atomicAdd(&h[d], 1);
    }
    __syncthreads();
    if (threadIdx.x < NB) {
        int v = h[threadIdx.x];
        if (v) atomicAdd(&hist[threadIdx.x], v);
    }
}

__global__ void k_scan(const int* __restrict__ hist, int* __restrict__ binBase) {
    int lane = threadIdx.x;  // blockDim.x == 64
    int v = hist[lane];
    int x = v;
#pragma unroll
    for (int d = 1; d < 64; d <<= 1) {
        int y = __shfl_up(x, d);
        if (lane >= d) x += y;
    }
    binBase[lane] = x - v;
}

__global__ void k_sortscatter(const int* __restrict__ cnt, const int* __restrict__ binBase,
                              int* __restrict__ binCursor, int* __restrict__ perm, int N) {
    __shared__ int lh[NB];
    __shared__ int lbase[NB];
    if (threadIdx.x < NB) lh[threadIdx.x] = 0;
    __syncthreads();
    int i = blockIdx.x * blockDim.x + threadIdx.x;
    int d = 0, lr = 0;
    bool valid = (i < N);
    if (valid) {
        d = cnt[i]; if (d > NB - 1) d = NB - 1;
        lr = atomicAdd(&lh[d], 1);
    }
    __syncthreads();
    if (threadIdx.x < NB) {
        int c = lh[threadIdx.x];
        lbase[threadIdx.x] = c ? atomicAdd(&binCursor[threadIdx.x], c) : 0;
    }
    __syncthreads();
    if (valid) perm[binBase[d] + lbase[d] + lr] = i;
}

__global__ void k_cast(const float* __restrict__ X, unsigned short* __restrict__ Y, int n8) {
    int i = blockIdx.x * blockDim.x + threadIdx.x;
    if (i >= n8) return;
    const float4* p = (const float4*)X + (size_t)i * 2;
    float4 a = p[0], b = p[1];
    ushort8v o;
    o[0] = f2b(a.x); o[1] = f2b(a.y); o[2] = f2b(a.z); o[3] = f2b(a.w);
    o[4] = f2b(b.x); o[5] = f2b(b.y); o[6] = f2b(b.z); o[7] = f2b(b.w);
    *(ushort8v*)&Y[(size_t)i * 8] = o;
}

__global__ void k_wpack4(const float* __restrict__ W0, const float* __restrict__ W1,
                         const float* __restrict__ W2, const float* __restrict__ W3,
                         unsigned short* __restrict__ out) {
    int t = blockIdx.x * blockDim.x + threadIdx.x;  // 0..2047
    if (t >= 2048) return;
    const float* W = (blockIdx.y == 0) ? W0 : (blockIdx.y == 1) ? W1
                   : (blockIdx.y == 2) ? W2 : W3;
    unsigned short* o = out + (size_t)blockIdx.y * 16384;
    int lane = t & 63;
    int nt = (t >> 6) & 7;
    int kk = t >> 9;
    int n = nt * 16 + (lane & 15);
    int k0 = kk * 32 + (lane >> 4) * 8;
    ushort8v h8;
#pragma unroll
    for (int j = 0; j < 8; ++j) h8[j] = f2b(W[(size_t)(k0 + j) * DIMS + n]);
    *(ushort8v*)&o[(size_t)t * 8] = h8;
}

// ---------------- gather, degree-sorted, 16 lanes/node, 4-deep ILP ----------------
__global__ __launch_bounds__(256) void k_gather_b5(
    const unsigned short* __restrict__ Xb, const float* __restrict__ dinv,
    const int* __restrict__ row_ptr, const int* __restrict__ cnt,
    const int* __restrict__ col, const int* __restrict__ perm,
    unsigned short* __restrict__ aggb, int N)
{
    int t = blockIdx.x * blockDim.x + threadIdx.x;
    int g = t >> 4;
    if (g >= N) return;
    const int node = perm[g];
    const size_t base = (size_t)(t & 15) * 8;

    float ds = dinv[node];
    float w0 = ds * ds;
    ushort8v sv = *(const ushort8v*)&Xb[(size_t)node * DIMS + base];
    float acc[8];
#pragma unroll
    for (int q = 0; q < 8; ++q) acc[q] = b2f(sv[q]) * w0;

    const int beg = row_ptr[node];
    const int m = cnt[node];
    int j = 0;
    for (; j + 3 < m; j += 4) {
        int s0 = col[beg + j],     s1 = col[beg + j + 1];
        int s2 = col[beg + j + 2], s3 = col[beg + j + 3];
        float wA = ds * dinv[s0], wB = ds * dinv[s1];
        float wC = ds * dinv[s2], wD = ds * dinv[s3];
        ushort8v v0 = *(const ushort8v*)&Xb[(size_t)s0 * DIMS + base];
        ushort8v v1 = *(const ushort8v*)&Xb[(size_t)s1 * DIMS + base];
        ushort8v v2 = *(const ushort8v*)&Xb[(size_t)s2 * DIMS + base];
        ushort8v v3 = *(const ushort8v*)&Xb[(size_t)s3 * DIMS + base];
#pragma unroll
        for (int q = 0; q < 8; ++q) acc[q] = fmaf(wA, b2f(v0[q]), acc[q]);
#pragma unroll
        for (int q = 0; q < 8; ++q) acc[q] = fmaf(wB, b2f(v1[q]), acc[q]);
#pragma unroll
        for (int q = 0; q < 8; ++q) acc[q] = fmaf(wC, b2f(v2[q]), acc[q]);
#pragma unroll
        for (int q = 0; q < 8; ++q) acc[q] = fmaf(wD, b2f(v3[q]), acc[q]);
    }
    for (; j < m; ++j) {
        int s0 = col[beg + j];
        float wA = ds * dinv[s0];
        ushort8v v0 = *(const ushort8v*)&Xb[(size_t)s0 * DIMS + base];
#pragma unroll
        for (int q = 0; q < 8; ++q) acc[q] = fmaf(wA, b2f(v0[q]), acc[q]);
    }
    ushort8v o;
#pragma unroll
    for (int q = 0; q < 8; ++q) o[q] = f2b(acc[q]);
    *(ushort8v*)&aggb[(size_t)node * DIMS + base] = o;
}

// ---------------- MFMA dual-GEMM + coupling, v5: column-half blocks, 32KB LDS ----------------
__global__ __launch_bounds__(256) void k_mfma_couple5(
    const unsigned short* __restrict__ Ab, const unsigned short* __restrict__ Wpk,
    const float* __restrict__ bs, const float* __restrict__ bt,
    const float* __restrict__ Xo, float* __restrict__ Out,
    unsigned short* OutB, int N, int nidx)
{
    __shared__ unsigned short lds[16384];  // 32 KB: Ws half | Wt half

    const int wave = threadIdx.x >> 6, lane = threadIdx.x & 63;
    const int rsub = lane & 15;
    const int ksub = (lane >> 4) * 8;
    const int csub = (lane >> 4) * 4;

    const int h = blockIdx.x & 1;

    for (int i = threadIdx.x; i < 2048; i += 256) {
        int wsel = i >> 10;
        int rem = i & 1023;
        int kk = rem >> 8;
        int ntl = (rem >> 6) & 3;
        int ln = rem & 63;
        int gfrag = (kk * 8 + h * 4 + ntl) * 64 + ln;
        *(ushort8v*)&lds[(size_t)i * 8] =
            *(const ushort8v*)&Wpk[((size_t)wsel * 16384) + (size_t)gfrag * 8];
    }
    __syncthreads();
    const unsigned short* wsf = lds;
    const unsigned short* wtf = lds + 8192;

    for (int idx = blockIdx.x; idx < nidx; idx += gridDim.x) {
        const int tile = idx >> 1;
        const int m = tile * 64 + wave * 16 + rsub;
        const int mld = (m < N) ? m : (N - 1);
        const bool valid = (m < N);

        bf16x8 af[4];
#pragma unroll
        for (int kk = 0; kk < 4; ++kk)
            af[kk] = *(const bf16x8*)&Ab[(size_t)mld * DIMS + kk * 32 + ksub];

        f32x4 acc_s[4], acc_t[4];
#pragma unroll
        for (int nt = 0; nt < 4; ++nt) {
            acc_s[nt] = (f32x4){0.f, 0.f, 0.f, 0.f};
            acc_t[nt] = (f32x4){0.f, 0.f, 0.f, 0.f};
        }

#pragma unroll
        for (int kk = 0; kk < 4; ++kk) {
#pragma unroll
            for (int nt = 0; nt < 4; ++nt) {
                const int fi = ((kk * 4 + nt) * 64 + lane) * 8;
                bf16x8 ws = *(const bf16x8*)&wsf[fi];
                bf16x8 wt = *(const bf16x8*)&wtf[fi];
                acc_s[nt] = __builtin_amdgcn_mfma_f32_16x16x32_bf16(ws, af[kk], acc_s[nt], 0, 0, 0);
                acc_t[nt] = __builtin_amdgcn_mfma_f32_16x16x32_bf16(wt, af[kk], acc_t[nt], 0, 0, 0);
            }
        }

        if (valid) {
#pragma unroll
            for (int nt = 0; nt < 4; ++nt) {
                const int c4 = (h * 4 + nt) * 16 + csub;
                float4 bsv = *(const float4*)&bs[c4];
                float4 btv = *(const float4*)&bt[c4];
                float4 xo  = *(const float4*)&Xo[(size_t)m * DIMS + c4];
                float4 o;
                o.x = xo.x * expf(tanhf(acc_s[nt][0] + bsv.x)) + (acc_t[nt][0] + btv.x);
                o.y = xo.y * expf(tanhf(acc_s[nt][1] + bsv.y)) + (acc_t[nt][1] + btv.y);
                o.z = xo.z * expf(tanhf(acc_s[nt][2] + bsv.z)) + (acc_t[nt][2] + btv.z);
                o.w = xo.w * expf(tanhf(acc_s[nt][3] + bsv.w)) + (acc_t[nt][3] + btv.w);
                *(float4*)&Out[(size_t)m * DIMS + c4] = o;
                if (OutB) {
                    ushort4 ob;
                    ob.x = f2b(o.x); ob.y = f2b(o.y); ob.z = f2b(o.z); ob.w = f2b(o.w);
                    *(ushort4*)&OutB[(size_t)m * DIMS + c4] = ob;
                }
            }
        }
    }
}

// ---------------- f32 fallback kernels ----------------
__global__ void k_fill(const int* __restrict__ src, const int* __restrict__ dst,
                       const int* __restrict__ row_ptr, int* __restrict__ cursor,
                       const float* __restrict__ dinv,
                       int* __restrict__ col, float* __restrict__ wgt, int E) {
    int e = blockIdx.x * blockDim.x + threadIdx.x;
    if (e >= E) return;
    int s = src[e], d = dst[e];
    int pos = row_ptr[d] + atomicAdd(&cursor[d], 1);
    col[pos] = s;
    wgt[pos] = dinv[s] * dinv[d];
}

__global__ __launch_bounds__(256) void k_gather(
    const float4* __restrict__ X4, const float* __restrict__ dinv,
    const int* __restrict__ row_ptr, const int* __restrict__ cnt,
    const int* __restrict__ col, const float* __restrict__ wgt,
    float4* __restrict__ agg4, int N)
{
    int t = blockIdx.x * blockDim.x + threadIdx.x;
    int node = t >> 5;
    if (node >= N) return;
    int lane = t & 31;
    float ds = dinv[node];
    float w0 = ds * ds;
    float4 acc = X4[(size_t)node * 32 + lane];
    acc.x *= w0; acc.y *= w0; acc.z *= w0; acc.w *= w0;
    int beg = row_ptr[node];
    int m = cnt[node];
    for (int j = 0; j < m; ++j) {
        int s0 = col[beg + j];
        float wa = wgt[beg + j];
        float4 v0 = X4[(size_t)s0 * 32 + lane];
        acc.x = fmaf(wa, v0.x, acc.x); acc.y = fmaf(wa, v0.y, acc.y);
        acc.z = fmaf(wa, v0.z, acc.z); acc.w = fmaf(wa, v0.w, acc.w);
    }
    agg4[(size_t)node * 32 + lane] = acc;
}

__global__ __launch_bounds__(256) void k_gemm_couple(
    const float* A, const float* __restrict__ Ws, const float* __restrict__ bs,
    const float* __restrict__ Wt, const float* __restrict__ bt,
    const float* __restrict__ Xo, float* Out, int N)
{
    constexpr int TM = 64, TK = 16;
    __shared__ float As[TK][TM + 4];
    __shared__ float Ss[TK][DIMS];
    __shared__ float St[TK][DIMS];
    const int tid = threadIdx.x;
    const int ty = tid >> 4, tx = tid & 15;
    const int r0 = ty * 4, c0 = tx * 8;
    const int block_row = blockIdx.x * TM;

    float acc_s[4][8], acc_t[4][8];
#pragma unroll
    for (int r = 0; r < 4; ++r)
#pragma unroll
        for (int c = 0; c < 8; ++c) { acc_s[r][c] = 0.f; acc_t[r][c] = 0.f; }

    const int ar = tid >> 2;
    const int aq = tid & 3;
    int arow = block_row + ar;
    if (arow >= N) arow = N - 1;

    for (int k0 = 0; k0 < DIMS; k0 += TK) {
        __syncthreads();
        {
            float4 v = *(const float4*)&A[(size_t)arow * DIMS + k0 + aq * 4];
            As[aq * 4 + 0][ar] = v.x;
            As[aq * 4 + 1][ar] = v.y;
            As[aq * 4 + 2][ar] = v.z;
            As[aq * 4 + 3][ar] = v.w;
        }
#pragma unroll
        for (int i = 0; i < 2; ++i) {
            int idx = tid + i * 256;
            int kk = idx >> 5;
            int j4 = idx & 31;
            *(float4*)&Ss[kk][j4 * 4] = *(const float4*)&Ws[(size_t)(k0 + kk) * DIMS + j4 * 4];
            *(float4*)&St[kk][j4 * 4] = *(const float4*)&Wt[(size_t)(k0 + kk) * DIMS + j4 * 4];
        }
        __syncthreads();
#pragma unroll
        for (int k = 0; k < TK; ++k) {
            float4 av = *(const float4*)&As[k][r0];
            float a[4] = {av.x, av.y, av.z, av.w};
            float ws8[8], wt8[8];
            *(float4*)&ws8[0] = *(const float4*)&Ss[k][c0];
            *(float4*)&ws8[4] = *(const float4*)&Ss[k][c0 + 4];
            *(float4*)&wt8[0] = *(const float4*)&St[k][c0];
            *(float4*)&wt8[4] = *(const float4*)&St[k][c0 + 4];
#pragma unroll
            for (int r = 0; r < 4; ++r)
#pragma unroll
                for (int c = 0; c < 8; ++c) {
                    acc_s[r][c] = fmaf(a[r], ws8[c], acc_s[r][c]);
                    acc_t[r][c] = fmaf(a[r], wt8[c], acc_t[r][c]);
                }
        }
    }

    float bsv[8], btv[8];
    *(float4*)&bsv[0] = *(const float4*)&bs[c0];
    *(float4*)&bsv[4] = *(const float4*)&bs[c0 + 4];
    *(float4*)&btv[0] = *(const float4*)&bt[c0];
    *(float4*)&btv[4] = *(const float4*)&bt[c0 + 4];
#pragma unroll
    for (int r = 0; r < 4; ++r) {
        int row = block_row + r0 + r;
        if (row < N) {
            float xo[8];
            *(float4*)&xo[0] = *(const float4*)&Xo[(size_t)row * DIMS + c0];
            *(float4*)&xo[4] = *(const float4*)&Xo[(size_t)row * DIMS + c0 + 4];
            float o[8];
#pragma unroll
            for (int c = 0; c < 8; ++c) {
                float s = tanhf(acc_s[r][c] + bsv[c]);
                float t = acc_t[r][c] + btv[c];
                o[c] = xo[c] * expf(s) + t;
            }
            *(float4*)&Out[(size_t)row * DIMS + c0] = *(const float4*)&o[0];
            *(float4*)&Out[(size_t)row * DIMS + c0 + 4] = *(const float4*)&o[4];
        }
    }
}

extern "C" void kernel_launch(void* const* d_in, const int* in_sizes, int n_in,
                              void* d_out, int out_size, void* d_ws, size_t ws_size,
                              hipStream_t stream) {
    const float* x_main  = (const float*)d_in[0];
    const float* x_guide = (const float*)d_in[1];
    const int*   ei      = (const int*)d_in[2];
    const float* Ws1 = (const float*)d_in[3];
    const float* bs1 = (const float*)d_in[4];
    const float* Wt1 = (const float*)d_in[5];
    const float* bt1 = (const float*)d_in[6];
    const float* Ws2 = (const float*)d_in[7];
    const float* bs2 = (const float*)d_in[8];
    const float* Wt2 = (const float*)d_in[9];
    const float* bt2 = (const float*)d_in[10];

    const int N = in_sizes[0] / DIMS;
    const int E = in_sizes[2] / 2;
    const int* src = ei;
    const int* dst = ei + E;

    float* out_main  = (float*)d_out;
    float* out_guide = out_main + (size_t)N * DIMS;

    // ---- ws layout ----
    char* w = (char*)d_ws;
    size_t off = 0;
    auto alloc = [&](size_t bytes) { size_t o = off; off = (off + bytes + 15) & ~(size_t)15; return o; };
    int*   cnt      = (int*)(w + alloc((size_t)N * 4));
    int*   row_ptr  = (int*)(w + alloc((size_t)N * 4));
    int*   bumpBlk  = (int*)(w + alloc(1024));   // bump | hist[64] | binCursor[64]
    int*   bump      = bumpBlk;
    int*   hist      = bumpBlk + 64;
    int*   binCursor = bumpBlk + 128;
    int*   binBase  = (int*)(w + alloc(256));
    int*   bktCnt    = (int*)(w + alloc(512 * 16 * 4));  // padded stride 16
    int*   bktCursor = (int*)(w + alloc(512 * 16 * 4));
    int*   bktBase   = (int*)(w + alloc(513 * 4));
    float* dinv     = (float*)(w + alloc((size_t)N * 4));
    int*   col      = (int*)(w + alloc((size_t)E * 4));
    int*   perm     = (int*)(w + alloc((size_t)N * 4));
    size_t base_end = off;
    unsigned short* xb   = (unsigned short*)(w + alloc((size_t)N * DIMS * 2));
    unsigned short* aggb = (unsigned short*)(w + alloc((size_t)N * DIMS * 2));
    unsigned short* wpk  = (unsigned short*)(w + alloc((size_t)4 * 16384 * 2));
    size_t needed_mfma = off;
    int*  slot  = (int*)aggb;    // old path: slot[E] aliases aggb
    int2* einfo = (int2*)aggb;   // new path: einfo[E] (8B) aliases aggb
    int*   cursor_fb = (int*)(w + base_end);
    float* wgt_fb    = (float*)(w + base_end + (((size_t)N * 4 + 15) & ~(size_t)15));
    size_t needed_f32 = base_end + ((size_t)N * 4 + 16) + (size_t)E * 4;

    const int gemm_grid  = (N + 63) / 64;
    const int ntiles64   = (N + 63) / 64;
    const int nidx       = ntiles64 * 2;
    int mfma_grid        = (nidx < 1024) ? nidx : 1024;
    mfma_grid            = (mfma_grid + 1) & ~1;

    const int nbkt = (N + 511) >> 9;
    const bool bucketed_ok = (nbkt <= 512) && ((size_t)E * 8 <= (size_t)N * DIMS * 2);

    if (ws_size >= needed_mfma) {
        hipMemsetAsync(bumpBlk, 0, 1024, stream);

        if (bucketed_ok) {
            // ---- bucketed CSR build (LDS atomics; ~50K global returning atomics) ----
            const int Ec = (E + 255) / 256;
            hipMemsetAsync(bktCnt, 0, (size_t)nbkt * 16 * 4, stream);
            k_bhist<<<256, 1024, 0, stream>>>(dst, bktCnt, E, nbkt, Ec);
            k_bscan<<<1, 64, 0, stream>>>(bktCnt, bktBase, bktCursor, nbkt, E);
            k_bscatter<<<256, 1024, 0, stream>>>(src, dst, bktCursor, einfo, E, nbkt, Ec);
            k_bcsr<<<nbkt, 512, 0, stream>>>(einfo, bktBase, col, row_ptr, cnt, N);
        } else {
            // ---- old CSR build ----
            hipMemsetAsync(cnt, 0, (size_t)N * 4, stream);
            k_count_slot<<<(E + 255) / 256, 256, 0, stream>>>(dst, cnt, slot, E);
            k_alloc<<<(N + 255) / 256, 256, 0, stream>>>(cnt, row_ptr, bump, N);
            k_fill3<<<(E + 255) / 256, 256, 0, stream>>>(src, dst, row_ptr, slot, col, E);
        }

        k_dinv2h<<<(N + 255) / 256, 256, 0, stream>>>(cnt, dinv, hist, N);
        k_scan<<<1, 64, 0, stream>>>(hist, binBase);
        k_sortscatter<<<(N + 255) / 256, 256, 0, stream>>>(cnt, binBase, binCursor, perm, N);

        k_wpack4<<<dim3(8, 4), 256, 0, stream>>>(Ws1, Wt1, Ws2, Wt2, wpk);
        unsigned short* W1pk = wpk;
        unsigned short* W2pk = wpk + 2 * 16384;

        const int n8 = N * DIMS / 8;
        k_cast<<<(n8 + 255) / 256, 256, 0, stream>>>(x_guide, xb, n8);

        const int gather_grid = (N * 16 + 255) / 256;
        // ---- stage 1 ----
        k_gather_b5<<<gather_grid, 256, 0, stream>>>(xb, dinv, row_ptr, cnt, col, perm, aggb, N);
        k_mfma_couple5<<<mfma_grid, 256, 0, stream>>>(aggb, W1pk, bs1, bt1, x_main,
                                                      out_main, xb, N, nidx);
        // ---- stage 2 ----
        k_gather_b5<<<gather_grid, 256, 0, stream>>>(xb, dinv, row_ptr, cnt, col, perm, aggb, N);
        k_mfma_couple5<<<mfma_grid, 256, 0, stream>>>(aggb, W2pk, bs2, bt2, x_guide,
                                                      out_guide, nullptr, N, nidx);
    } else if (ws_size >= needed_f32) {
        float* agg = out_guide;
        hipMemsetAsync(cnt, 0, (size_t)N * 4, stream);
        hipMemsetAsync(bumpBlk, 0, 1024, stream);
        hipMemsetAsync(cursor_fb, 0, (size_t)N * 4, stream);
        k_count_slot<<<(E + 255) / 256, 256, 0, stream>>>(dst, cnt, col, E);
        k_dinv2h<<<(N + 255) / 256, 256, 0, stream>>>(cnt, dinv, hist, N);
        k_alloc<<<(N + 255) / 256, 256, 0, stream>>>(cnt, row_ptr, bump, N);
        k_fill<<<(E + 255) / 256, 256, 0, stream>>>(src, dst, row_ptr, cursor_fb, dinv, col, wgt_fb, E);
        const int gather_grid32 = (N * 32 + 255) / 256;
        k_gather<<<gather_grid32, 256, 0, stream>>>((const float4*)x_guide, dinv, row_ptr, cnt,
                                                    col, wgt_fb, (float4*)agg, N);
        k_gemm_couple<<<gemm_grid, 256, 0, stream>>>(agg, Ws1, bs1, Wt1, bt1, x_main, out_main, N);
        k_gather<<<gather_grid32, 256, 0, stream>>>((const float4*)out_main, dinv, row_ptr, cnt,
                                                    col, wgt_fb, (float4*)agg, N);
        k_gemm_couple<<<gemm_grid, 256, 0, stream>>>(agg, Ws2, bs2, Wt2, bt2, x_guide, out_guide, N);
    }
}

// Round 11
// 332.923 us; speedup vs baseline: 1.6086x; 1.0866x over previous
//
#include <hip/hip_runtime.h>
#include <cstdint>
#include <cstddef>

constexpr int DIMS = 128;

typedef __attribute__((ext_vector_type(8))) short bf16x8;
typedef __attribute__((ext_vector_type(8))) unsigned short ushort8v;
typedef __attribute__((ext_vector_type(4))) float f32x4;

__device__ __forceinline__ unsigned short f2b(float f) {
    uint32_t u = __builtin_bit_cast(uint32_t, f);
    uint32_t r = (u + 0x7FFFu + ((u >> 16) & 1u)) >> 16;
    return (unsigned short)r;
}
__device__ __forceinline__ float b2f(unsigned short h) {
    uint32_t u = ((uint32_t)h) << 16;
    return __builtin_bit_cast(float, u);
}

// ================= bucketed CSR build (LDS atomics, packed edges) =================
// Coarse buckets of 512 nodes: bucket(d) = d >> 9. Packed edge: (src<<9)|(d&511).

__global__ __launch_bounds__(1024) void k_bhist(const int* __restrict__ dst,
                                                int* __restrict__ bktCnt,
                                                int E, int nbkt, int Ec) {
    __shared__ int lh[512];
    if (threadIdx.x < 512) lh[threadIdx.x] = 0;
    __syncthreads();
    int base = blockIdx.x * Ec;
    int end = min(E, base + Ec);
    for (int i = base + threadIdx.x; i < end; i += 1024)
        atomicAdd(&lh[dst[i] >> 9], 1);
    __syncthreads();
    if (threadIdx.x < nbkt) {
        int v = lh[threadIdx.x];
        if (v) atomicAdd(&bktCnt[threadIdx.x * 16], v);
    }
}

__global__ void k_bscan(const int* __restrict__ bktCnt, int* __restrict__ bktBase,
                        int* __restrict__ bktCursor, int nbkt, int E) {
    int lane = threadIdx.x;  // blockDim.x == 64
    int v[8]; int s = 0;
#pragma unroll
    for (int k = 0; k < 8; ++k) {
        int idx = lane * 8 + k;
        int c = (idx < nbkt) ? bktCnt[idx * 16] : 0;
        v[k] = s; s += c;
    }
    int x = s;
#pragma unroll
    for (int d = 1; d < 64; d <<= 1) {
        int y = __shfl_up(x, d);
        if (lane >= d) x += y;
    }
    int excl = x - s;
#pragma unroll
    for (int k = 0; k < 8; ++k) {
        int idx = lane * 8 + k;
        if (idx < nbkt) { int bb = excl + v[k]; bktBase[idx] = bb; bktCursor[idx * 16] = bb; }
    }
    if (lane == 0) bktBase[nbkt] = E;
}

__global__ __launch_bounds__(1024) void k_bscatter(const int* __restrict__ src,
                                                   const int* __restrict__ dst,
                                                   int* __restrict__ bktCursor,
                                                   unsigned int* __restrict__ epk,
                                                   int E, int nbkt, int Ec) {
    __shared__ int lh[512];
    __shared__ int lbase[512];
    __shared__ int lcur[512];
    if (threadIdx.x < 512) { lh[threadIdx.x] = 0; lcur[threadIdx.x] = 0; }
    __syncthreads();
    int base = blockIdx.x * Ec;
    int end = min(E, base + Ec);
    for (int i = base + threadIdx.x; i < end; i += 1024)
        atomicAdd(&lh[dst[i] >> 9], 1);
    __syncthreads();
    if (threadIdx.x < nbkt) {
        int c = lh[threadIdx.x];
        lbase[threadIdx.x] = c ? atomicAdd(&bktCursor[threadIdx.x * 16], c) : 0;
    }
    __syncthreads();
    for (int i = base + threadIdx.x; i < end; i += 1024) {
        int d = dst[i], s = src[i];
        int b = d >> 9;
        int r = atomicAdd(&lcur[b], 1);
        epk[lbase[b] + r] = ((unsigned int)s << 9) | (unsigned int)(d & 511);
    }
}

__global__ __launch_bounds__(512) void k_bcsr(const unsigned int* __restrict__ epk,
                                              const int* __restrict__ bktBase,
                                              int* __restrict__ col, int* __restrict__ row_ptr,
                                              int* __restrict__ cnt, int N) {
    __shared__ int lcnt[512];
    __shared__ int loff[512];
    __shared__ int lcur[512];
    const int b = blockIdx.x;
    const int node0 = b << 9;
    lcnt[threadIdx.x] = 0; lcur[threadIdx.x] = 0;
    __syncthreads();
    const int ebeg = bktBase[b], eend = bktBase[b + 1];
    for (int i = ebeg + threadIdx.x; i < eend; i += 512)
        atomicAdd(&lcnt[epk[i] & 511u], 1);
    __syncthreads();
    if (threadIdx.x < 64) {
        int lane = threadIdx.x;
        int v[8]; int s = 0;
#pragma unroll
        for (int k = 0; k < 8; ++k) { v[k] = s; s += lcnt[lane * 8 + k]; }
        int x = s;
#pragma unroll
        for (int d = 1; d < 64; d <<= 1) { int y = __shfl_up(x, d); if (lane >= d) x += y; }
        int excl = x - s;
#pragma unroll
        for (int k = 0; k < 8; ++k) loff[lane * 8 + k] = excl + v[k];
    }
    __syncthreads();
    const int node = node0 + threadIdx.x;
    if (node < N) {
        row_ptr[node] = ebeg + loff[threadIdx.x];
        cnt[node] = lcnt[threadIdx.x];
    }
    for (int i = ebeg + threadIdx.x; i < eend; i += 512) {
        unsigned int e = epk[i];
        int dl = e & 511u;
        int r = atomicAdd(&lcur[dl], 1);
        col[ebeg + loff[dl] + r] = (int)(e >> 9);
    }
}

// ================= old-path CSR kernels (fallback) =================
__global__ void k_count_slot(const int* __restrict__ dst, int* __restrict__ cnt,
                             int* __restrict__ slot, int E) {
    int e = blockIdx.x * blockDim.x + threadIdx.x;
    if (e < E) slot[e] = atomicAdd(&cnt[dst[e]], 1);
}

__global__ void k_alloc(const int* __restrict__ cnt, int* __restrict__ row_ptr,
                        int* __restrict__ bump, int N) {
    int i = blockIdx.x * blockDim.x + threadIdx.x;
    int lane = threadIdx.x & 63;
    int v = (i < N) ? cnt[i] : 0;
    int x = v;
#pragma unroll
    for (int d = 1; d < 64; d <<= 1) {
        int y = __shfl_up(x, d);
        if (lane >= d) x += y;
    }
    int total = __shfl(x, 63);
    int base = 0;
    if (lane == 0) base = atomicAdd(bump, total);
    base = __shfl(base, 0);
    if (i < N) row_ptr[i] = base + x - v;
}

__global__ void k_fill3(const int* __restrict__ src, const int* __restrict__ dst,
                        const int* __restrict__ row_ptr, const int* __restrict__ slot,
                        int* __restrict__ col, int E) {
    int e = blockIdx.x * blockDim.x + threadIdx.x;
    if (e >= E) return;
    col[row_ptr[dst[e]] + slot[e]] = src[e];
}

// ================= shared small kernels =================
__global__ void k_dinv2(const int* __restrict__ cnt, float* __restrict__ dinv, int N) {
    int i = blockIdx.x * blockDim.x + threadIdx.x;
    if (i < N) dinv[i] = rsqrtf((float)(cnt[i] + 1));
}

__global__ void k_cast(const float* __restrict__ X, unsigned short* __restrict__ Y, int n8) {
    int i = blockIdx.x * blockDim.x + threadIdx.x;
    if (i >= n8) return;
    const float4* p = (const float4*)X + (size_t)i * 2;
    float4 a = p[0], b = p[1];
    ushort8v o;
    o[0] = f2b(a.x); o[1] = f2b(a.y); o[2] = f2b(a.z); o[3] = f2b(a.w);
    o[4] = f2b(b.x); o[5] = f2b(b.y); o[6] = f2b(b.z); o[7] = f2b(b.w);
    *(ushort8v*)&Y[(size_t)i * 8] = o;
}

__global__ void k_wpack4(const float* __restrict__ W0, const float* __restrict__ W1,
                         const float* __restrict__ W2, const float* __restrict__ W3,
                         unsigned short* __restrict__ out) {
    int t = blockIdx.x * blockDim.x + threadIdx.x;  // 0..2047
    if (t >= 2048) return;
    const float* W = (blockIdx.y == 0) ? W0 : (blockIdx.y == 1) ? W1
                   : (blockIdx.y == 2) ? W2 : W3;
    unsigned short* o = out + (size_t)blockIdx.y * 16384;
    int lane = t & 63;
    int nt = (t >> 6) & 7;
    int kk = t >> 9;
    int n = nt * 16 + (lane & 15);
    int k0 = kk * 32 + (lane >> 4) * 8;
    ushort8v h8;
#pragma unroll
    for (int j = 0; j < 8; ++j) h8[j] = f2b(W[(size_t)(k0 + j) * DIMS + n]);
    *(ushort8v*)&o[(size_t)t * 8] = h8;
}

// ---------------- gather (bf16 in/out), identity order, 16 lanes/node, 2-deep ----------------
__global__ __launch_bounds__(256) void k_gather_b3(
    const unsigned short* __restrict__ Xb, const float* __restrict__ dinv,
    const int* __restrict__ row_ptr, const int* __restrict__ cnt,
    const int* __restrict__ col, unsigned short* __restrict__ aggb, int N)
{
    int t = blockIdx.x * blockDim.x + threadIdx.x;
    int node = t >> 4;
    if (node >= N) return;
    const size_t base = (size_t)(t & 15) * 8;

    float ds = dinv[node];
    float w0 = ds * ds;
    ushort8v sv = *(const ushort8v*)&Xb[(size_t)node * DIMS + base];
    float acc[8];
#pragma unroll
    for (int q = 0; q < 8; ++q) acc[q] = b2f(sv[q]) * w0;

    const int beg = row_ptr[node];
    const int m = cnt[node];
    int j = 0;
    for (; j + 1 < m; j += 2) {
        int s0 = col[beg + j], s1 = col[beg + j + 1];
        float wa = ds * dinv[s0], wb = ds * dinv[s1];
        ushort8v v0 = *(const ushort8v*)&Xb[(size_t)s0 * DIMS + base];
        ushort8v v1 = *(const ushort8v*)&Xb[(size_t)s1 * DIMS + base];
#pragma unroll
        for (int q = 0; q < 8; ++q) acc[q] = fmaf(wa, b2f(v0[q]), acc[q]);
#pragma unroll
        for (int q = 0; q < 8; ++q) acc[q] = fmaf(wb, b2f(v1[q]), acc[q]);
    }
    if (j < m) {
        int s0 = col[beg + j];
        float wa = ds * dinv[s0];
        ushort8v v0 = *(const ushort8v*)&Xb[(size_t)s0 * DIMS + base];
#pragma unroll
        for (int q = 0; q < 8; ++q) acc[q] = fmaf(wa, b2f(v0[q]), acc[q]);
    }
    ushort8v o;
#pragma unroll
    for (int q = 0; q < 8; ++q) o[q] = f2b(acc[q]);
    *(ushort8v*)&aggb[(size_t)node * DIMS + base] = o;
}

// ---------------- MFMA dual-GEMM + coupling, v5: column-half blocks, 32KB LDS ----------------
__global__ __launch_bounds__(256) void k_mfma_couple5(
    const unsigned short* __restrict__ Ab, const unsigned short* __restrict__ Wpk,
    const float* __restrict__ bs, const float* __restrict__ bt,
    const float* __restrict__ Xo, float* __restrict__ Out,
    unsigned short* OutB, int N, int nidx)
{
    __shared__ unsigned short lds[16384];  // 32 KB: Ws half | Wt half

    const int wave = threadIdx.x >> 6, lane = threadIdx.x & 63;
    const int rsub = lane & 15;
    const int ksub = (lane >> 4) * 8;
    const int csub = (lane >> 4) * 4;

    const int h = blockIdx.x & 1;

    for (int i = threadIdx.x; i < 2048; i += 256) {
        int wsel = i >> 10;
        int rem = i & 1023;
        int kk = rem >> 8;
        int ntl = (rem >> 6) & 3;
        int ln = rem & 63;
        int gfrag = (kk * 8 + h * 4 + ntl) * 64 + ln;
        *(ushort8v*)&lds[(size_t)i * 8] =
            *(const ushort8v*)&Wpk[((size_t)wsel * 16384) + (size_t)gfrag * 8];
    }
    __syncthreads();
    const unsigned short* wsf = lds;
    const unsigned short* wtf = lds + 8192;

    for (int idx = blockIdx.x; idx < nidx; idx += gridDim.x) {
        const int tile = idx >> 1;
        const int m = tile * 64 + wave * 16 + rsub;
        const int mld = (m < N) ? m : (N - 1);
        const bool valid = (m < N);

        bf16x8 af[4];
#pragma unroll
        for (int kk = 0; kk < 4; ++kk)
            af[kk] = *(const bf16x8*)&Ab[(size_t)mld * DIMS + kk * 32 + ksub];

        f32x4 acc_s[4], acc_t[4];
#pragma unroll
        for (int nt = 0; nt < 4; ++nt) {
            acc_s[nt] = (f32x4){0.f, 0.f, 0.f, 0.f};
            acc_t[nt] = (f32x4){0.f, 0.f, 0.f, 0.f};
        }

#pragma unroll
        for (int kk = 0; kk < 4; ++kk) {
#pragma unroll
            for (int nt = 0; nt < 4; ++nt) {
                const int fi = ((kk * 4 + nt) * 64 + lane) * 8;
                bf16x8 ws = *(const bf16x8*)&wsf[fi];
                bf16x8 wt = *(const bf16x8*)&wtf[fi];
                acc_s[nt] = __builtin_amdgcn_mfma_f32_16x16x32_bf16(ws, af[kk], acc_s[nt], 0, 0, 0);
                acc_t[nt] = __builtin_amdgcn_mfma_f32_16x16x32_bf16(wt, af[kk], acc_t[nt], 0, 0, 0);
            }
        }

        if (valid) {
#pragma unroll
            for (int nt = 0; nt < 4; ++nt) {
                const int c4 = (h * 4 + nt) * 16 + csub;
                float4 bsv = *(const float4*)&bs[c4];
                float4 btv = *(const float4*)&bt[c4];
                float4 xo  = *(const float4*)&Xo[(size_t)m * DIMS + c4];
                float4 o;
                o.x = xo.x * expf(tanhf(acc_s[nt][0] + bsv.x)) + (acc_t[nt][0] + btv.x);
                o.y = xo.y * expf(tanhf(acc_s[nt][1] + bsv.y)) + (acc_t[nt][1] + btv.y);
                o.z = xo.z * expf(tanhf(acc_s[nt][2] + bsv.z)) + (acc_t[nt][2] + btv.z);
                o.w = xo.w * expf(tanhf(acc_s[nt][3] + bsv.w)) + (acc_t[nt][3] + btv.w);
                *(float4*)&Out[(size_t)m * DIMS + c4] = o;
                if (OutB) {
                    ushort4 ob;
                    ob.x = f2b(o.x); ob.y = f2b(o.y); ob.z = f2b(o.z); ob.w = f2b(o.w);
                    *(ushort4*)&OutB[(size_t)m * DIMS + c4] = ob;
                }
            }
        }
    }
}

// ---------------- f32 fallback kernels ----------------
__global__ void k_fill(const int* __restrict__ src, const int* __restrict__ dst,
                       const int* __restrict__ row_ptr, int* __restrict__ cursor,
                       const float* __restrict__ dinv,
                       int* __restrict__ col, float* __restrict__ wgt, int E) {
    int e = blockIdx.x * blockDim.x + threadIdx.x;
    if (e >= E) return;
    int s = src[e], d = dst[e];
    int pos = row_ptr[d] + atomicAdd(&cursor[d], 1);
    col[pos] = s;
    wgt[pos] = dinv[s] * dinv[d];
}

__global__ __launch_bounds__(256) void k_gather(
    const float4* __restrict__ X4, const float* __restrict__ dinv,
    const int* __restrict__ row_ptr, const int* __restrict__ cnt,
    const int* __restrict__ col, const float* __restrict__ wgt,
    float4* __restrict__ agg4, int N)
{
    int t = blockIdx.x * blockDim.x + threadIdx.x;
    int node = t >> 5;
    if (node >= N) return;
    int lane = t & 31;
    float ds = dinv[node];
    float w0 = ds * ds;
    float4 acc = X4[(size_t)node * 32 + lane];
    acc.x *= w0; acc.y *= w0; acc.z *= w0; acc.w *= w0;
    int beg = row_ptr[node];
    int m = cnt[node];
    for (int j = 0; j < m; ++j) {
        int s0 = col[beg + j];
        float wa = wgt[beg + j];
        float4 v0 = X4[(size_t)s0 * 32 + lane];
        acc.x = fmaf(wa, v0.x, acc.x); acc.y = fmaf(wa, v0.y, acc.y);
        acc.z = fmaf(wa, v0.z, acc.z); acc.w = fmaf(wa, v0.w, acc.w);
    }
    agg4[(size_t)node * 32 + lane] = acc;
}

__global__ __launch_bounds__(256) void k_gemm_couple(
    const float* A, const float* __restrict__ Ws, const float* __restrict__ bs,
    const float* __restrict__ Wt, const float* __restrict__ bt,
    const float* __restrict__ Xo, float* Out, int N)
{
    constexpr int TM = 64, TK = 16;
    __shared__ float As[TK][TM + 4];
    __shared__ float Ss[TK][DIMS];
    __shared__ float St[TK][DIMS];
    const int tid = threadIdx.x;
    const int ty = tid >> 4, tx = tid & 15;
    const int r0 = ty * 4, c0 = tx * 8;
    const int block_row = blockIdx.x * TM;

    float acc_s[4][8], acc_t[4][8];
#pragma unroll
    for (int r = 0; r < 4; ++r)
#pragma unroll
        for (int c = 0; c < 8; ++c) { acc_s[r][c] = 0.f; acc_t[r][c] = 0.f; }

    const int ar = tid >> 2;
    const int aq = tid & 3;
    int arow = block_row + ar;
    if (arow >= N) arow = N - 1;

    for (int k0 = 0; k0 < DIMS; k0 += TK) {
        __syncthreads();
        {
            float4 v = *(const float4*)&A[(size_t)arow * DIMS + k0 + aq * 4];
            As[aq * 4 + 0][ar] = v.x;
            As[aq * 4 + 1][ar] = v.y;
            As[aq * 4 + 2][ar] = v.z;
            As[aq * 4 + 3][ar] = v.w;
        }
#pragma unroll
        for (int i = 0; i < 2; ++i) {
            int idx = tid + i * 256;
            int kk = idx >> 5;
            int j4 = idx & 31;
            *(float4*)&Ss[kk][j4 * 4] = *(const float4*)&Ws[(size_t)(k0 + kk) * DIMS + j4 * 4];
            *(float4*)&St[kk][j4 * 4] = *(const float4*)&Wt[(size_t)(k0 + kk) * DIMS + j4 * 4];
        }
        __syncthreads();
#pragma unroll
        for (int k = 0; k < TK; ++k) {
            float4 av = *(const float4*)&As[k][r0];
            float a[4] = {av.x, av.y, av.z, av.w};
            float ws8[8], wt8[8];
            *(float4*)&ws8[0] = *(const float4*)&Ss[k][c0];
            *(float4*)&ws8[4] = *(const float4*)&Ss[k][c0 + 4];
            *(float4*)&wt8[0] = *(const float4*)&St[k][c0];
            *(float4*)&wt8[4] = *(const float4*)&St[k][c0 + 4];
#pragma unroll
            for (int r = 0; r < 4; ++r)
#pragma unroll
                for (int c = 0; c < 8; ++c) {
                    acc_s[r][c] = fmaf(a[r], ws8[c], acc_s[r][c]);
                    acc_t[r][c] = fmaf(a[r], wt8[c], acc_t[r][c]);
                }
        }
    }

    float bsv[8], btv[8];
    *(float4*)&bsv[0] = *(const float4*)&bs[c0];
    *(float4*)&bsv[4] = *(const float4*)&bs[c0 + 4];
    *(float4*)&btv[0] = *(const float4*)&bt[c0];
    *(float4*)&btv[4] = *(const float4*)&bt[c0 + 4];
#pragma unroll
    for (int r = 0; r < 4; ++r) {
        int row = block_row + r0 + r;
        if (row < N) {
            float xo[8];
            *(float4*)&xo[0] = *(const float4*)&Xo[(size_t)row * DIMS + c0];
            *(float4*)&xo[4] = *(const float4*)&Xo[(size_t)row * DIMS + c0 + 4];
            float o[8];
#pragma unroll
            for (int c = 0; c < 8; ++c) {
                float s = tanhf(acc_s[r][c] + bsv[c]);
                float t = acc_t[r][c] + btv[c];
                o[c] = xo[c] * expf(s) + t;
            }
            *(float4*)&Out[(size_t)row * DIMS + c0] = *(const float4*)&o[0];
            *(float4*)&Out[(size_t)row * DIMS + c0 + 4] = *(const float4*)&o[4];
        }
    }
}

extern "C" void kernel_launch(void* const* d_in, const int* in_sizes, int n_in,
                              void* d_out, int out_size, void* d_ws, size_t ws_size,
                              hipStream_t stream) {
    const float* x_main  = (const float*)d_in[0];
    const float* x_guide = (const float*)d_in[1];
    const int*   ei      = (const int*)d_in[2];
    const float* Ws1 = (const float*)d_in[3];
    const float* bs1 = (const float*)d_in[4];
    const float* Wt1 = (const float*)d_in[5];
    const float* bt1 = (const float*)d_in[6];
    const float* Ws2 = (const float*)d_in[7];
    const float* bs2 = (const float*)d_in[8];
    const float* Wt2 = (const float*)d_in[9];
    const float* bt2 = (const float*)d_in[10];

    const int N = in_sizes[0] / DIMS;
    const int E = in_sizes[2] / 2;
    const int* src = ei;
    const int* dst = ei + E;

    float* out_main  = (float*)d_out;
    float* out_guide = out_main + (size_t)N * DIMS;

    // ---- ws layout ----
    char* w = (char*)d_ws;
    size_t off = 0;
    auto alloc = [&](size_t bytes) { size_t o = off; off = (off + bytes + 15) & ~(size_t)15; return o; };
    int*   cnt      = (int*)(w + alloc((size_t)N * 4));
    int*   row_ptr  = (int*)(w + alloc((size_t)N * 4));
    int*   bump     = (int*)(w + alloc(64));
    int*   bktCnt    = (int*)(w + alloc(512 * 16 * 4));  // padded stride 16
    int*   bktCursor = (int*)(w + alloc(512 * 16 * 4));
    int*   bktBase   = (int*)(w + alloc(513 * 4));
    float* dinv     = (float*)(w + alloc((size_t)N * 4));
    int*   col      = (int*)(w + alloc((size_t)E * 4));
    size_t base_end = off;
    unsigned short* xb   = (unsigned short*)(w + alloc((size_t)N * DIMS * 2));
    unsigned short* aggb = (unsigned short*)(w + alloc((size_t)N * DIMS * 2));
    unsigned short* wpk  = (unsigned short*)(w + alloc((size_t)4 * 16384 * 2));
    size_t needed_mfma = off;
    int*          slot = (int*)aggb;           // old path: slot[E] aliases aggb
    unsigned int* epk  = (unsigned int*)aggb;  // new path: packed edges alias aggb
    int*   cursor_fb = (int*)(w + base_end);
    float* wgt_fb    = (float*)(w + base_end + (((size_t)N * 4 + 15) & ~(size_t)15));
    size_t needed_f32 = base_end + ((size_t)N * 4 + 16) + (size_t)E * 4;

    const int gemm_grid  = (N + 63) / 64;
    const int ntiles64   = (N + 63) / 64;
    const int nidx       = ntiles64 * 2;
    int mfma_grid        = (nidx < 1024) ? nidx : 1024;
    mfma_grid            = (mfma_grid + 1) & ~1;

    const int nbkt = (N + 511) >> 9;
    const bool bucketed_ok = (nbkt <= 512) && (N < (1 << 23)) &&
                             ((size_t)E * 4 <= (size_t)N * DIMS * 2);

    if (ws_size >= needed_mfma) {
        if (bucketed_ok) {
            const int Ec = (E + 255) / 256;
            hipMemsetAsync(bktCnt, 0, (size_t)nbkt * 16 * 4, stream);
            k_bhist<<<256, 1024, 0, stream>>>(dst, bktCnt, E, nbkt, Ec);
            k_bscan<<<1, 64, 0, stream>>>(bktCnt, bktBase, bktCursor, nbkt, E);
            k_bscatter<<<256, 1024, 0, stream>>>(src, dst, bktCursor, epk, E, nbkt, Ec);
            k_bcsr<<<nbkt, 512, 0, stream>>>(epk, bktBase, col, row_ptr, cnt, N);
        } else {
            hipMemsetAsync(cnt, 0, (size_t)N * 4, stream);
            hipMemsetAsync(bump, 0, 64, stream);
            k_count_slot<<<(E + 255) / 256, 256, 0, stream>>>(dst, cnt, slot, E);
            k_alloc<<<(N + 255) / 256, 256, 0, stream>>>(cnt, row_ptr, bump, N);
            k_fill3<<<(E + 255) / 256, 256, 0, stream>>>(src, dst, row_ptr, slot, col, E);
        }

        k_dinv2<<<(N + 255) / 256, 256, 0, stream>>>(cnt, dinv, N);

        k_wpack4<<<dim3(8, 4), 256, 0, stream>>>(Ws1, Wt1, Ws2, Wt2, wpk);
        unsigned short* W1pk = wpk;
        unsigned short* W2pk = wpk + 2 * 16384;

        const int n8 = N * DIMS / 8;
        k_cast<<<(n8 + 255) / 256, 256, 0, stream>>>(x_guide, xb, n8);

        const int gather_grid = (N * 16 + 255) / 256;
        // ---- stage 1 ----
        k_gather_b3<<<gather_grid, 256, 0, stream>>>(xb, dinv, row_ptr, cnt, col, aggb, N);
        k_mfma_couple5<<<mfma_grid, 256, 0, stream>>>(aggb, W1pk, bs1, bt1, x_main,
                                                      out_main, xb, N, nidx);
        // ---- stage 2 ----
        k_gather_b3<<<gather_grid, 256, 0, stream>>>(xb, dinv, row_ptr, cnt, col, aggb, N);
        k_mfma_couple5<<<mfma_grid, 256, 0, stream>>>(aggb, W2pk, bs2, bt2, x_guide,
                                                      out_guide, nullptr, N, nidx);
    } else if (ws_size >= needed_f32) {
        float* agg = out_guide;
        hipMemsetAsync(cnt, 0, (size_t)N * 4, stream);
        hipMemsetAsync(bump, 0, 64, stream);
        hipMemsetAsync(cursor_fb, 0, (size_t)N * 4, stream);
        k_count_slot<<<(E + 255) / 256, 256, 0, stream>>>(dst, cnt, col, E);
        k_dinv2<<<(N + 255) / 256, 256, 0, stream>>>(cnt, dinv, N);
        k_alloc<<<(N + 255) / 256, 256, 0, stream>>>(cnt, row_ptr, bump, N);
        k_fill<<<(E + 255) / 256, 256, 0, stream>>>(src, dst, row_ptr, cursor_fb, dinv, col, wgt_fb, E);
        const int gather_grid32 = (N * 32 + 255) / 256;
        k_gather<<<gather_grid32, 256, 0, stream>>>((const float4*)x_guide, dinv, row_ptr, cnt,
                                                    col, wgt_fb, (float4*)agg, N);
        k_gemm_couple<<<gemm_grid, 256, 0, stream>>>(agg, Ws1, bs1, Wt1, bt1, x_main, out_main, N);
        k_gather<<<gather_grid32, 256, 0, stream>>>((const float4*)out_main, dinv, row_ptr, cnt,
                                                    col, wgt_fb, (float4*)agg, N);
        k_gemm_couple<<<gemm_grid, 256, 0, stream>>>(agg, Ws2, bs2, Wt2, bt2, x_guide, out_guide, N);
    }
}